// Round 9
// baseline (778.797 us; speedup 1.0000x reference)
//
#include <hip/hip_runtime.h>

typedef unsigned short u16;
typedef unsigned int   u32;
typedef unsigned long long u64;
using bf16x8 = __attribute__((ext_vector_type(8))) short;
using f32x4  = __attribute__((ext_vector_type(4))) float;

__device__ __forceinline__ float b2f(u16 u) {
    union { unsigned int i; float f; } x; x.i = ((unsigned int)u) << 16; return x.f;
}
__device__ __forceinline__ u16 f2b(float f) {
    union { float f; unsigned int i; } x; x.f = f;
    unsigned int i = x.i;
    return (u16)((i + 0x7FFFu + ((i >> 16) & 1u)) >> 16);  // RNE, inputs never NaN
}
// flag-aware scalar load of an INPUT tensor element (f32 or bf16 storage)
__device__ __forceinline__ float ldx(const void* p, size_t i, int f32) {
    return f32 ? ((const float*)p)[i] : b2f(((const u16*)p)[i]);
}
// async global->LDS, 16B per lane; lptr must be wave-uniform (HW: base+lane*16)
__device__ __forceinline__ void gload16(const void* g, void* l) {
    __builtin_amdgcn_global_load_lds(
        (const __attribute__((address_space(1))) void*)g,
        (__attribute__((address_space(3))) void*)l, 16, 0, 0);
}

// ---------------------------------------------------------------------------
// init_diag: diag[1] = inputs-are-f32 flag; diag[2] = mask-all-ones (refined
// by mask_bits_kernel).
// ---------------------------------------------------------------------------
__global__ __launch_bounds__(64) void init_diag(const u16* __restrict__ x, u32* diag)
{
    int lane = threadIdx.x;
    u16 v = x[lane * 2];
    int e = (v >> 7) & 0xFF;
    bool extreme = (e < 100) | (e > 154);
    u64 m = __ballot(extreme);
    if (lane == 0) { diag[0] = 0u; diag[1] = (m != 0ull) ? 1u : 0u; diag[2] = 1u; }
}

__global__ __launch_bounds__(256) void diag_fill_f32(float* __restrict__ out, float val, int n)
{
    for (int i = blockIdx.x * 256 + threadIdx.x; i < n; i += gridDim.x * 256) out[i] = val;
}

// ---------------------------------------------------------------------------
// xconv: x (f32 or bf16 per flag) -> contiguous bf16 copy.
// ---------------------------------------------------------------------------
__global__ __launch_bounds__(256) void xconv(
    const void* __restrict__ x, u16* __restrict__ xb, const u32* __restrict__ diag)
{
    const int f32 = (int)diag[1];
    size_t i0 = ((size_t)blockIdx.x * 256 + threadIdx.x) * 8;
    if (f32) {
        const float4* p = (const float4*)((const float*)x + i0);
        float4 a = p[0], b = p[1];
        bf16x8 v;
        v[0]=(short)f2b(a.x); v[1]=(short)f2b(a.y); v[2]=(short)f2b(a.z); v[3]=(short)f2b(a.w);
        v[4]=(short)f2b(b.x); v[5]=(short)f2b(b.y); v[6]=(short)f2b(b.z); v[7]=(short)f2b(b.w);
        *(bf16x8*)(xb + i0) = v;
    } else {
        *(bf16x8*)(xb + i0) = *(const bf16x8*)((const u16*)x + i0);
    }
}

// ---------------------------------------------------------------------------
// mask -> bitmask. R9: 4 ints per thread (int4), shfl-OR pack — 8192 blocks
// instead of 32768 (4x fewer waves for a 32 MB streaming read).
// mb[gw] bit j = mask[gw*64 + j] != 0   (gw = (b*1024+i)*16 + w).
// ---------------------------------------------------------------------------
__global__ __launch_bounds__(256) void mask_bits_kernel(
    const int* __restrict__ mask, u64* __restrict__ mb, u32* __restrict__ diag)
{
    int t = threadIdx.x;
    int lane = t & 63, wv = t >> 6;
    int gw0 = blockIdx.x * 16 + wv * 4 + (lane >> 4);    // this lane's u64 word
    const int4* p = (const int4*)(mask + (size_t)gw0 * 64 + (lane & 15) * 4);
    int4 m = *p;
    u64 v = ((u64)(m.x != 0)      | ((u64)(m.y != 0) << 1)
           | ((u64)(m.z != 0) << 2) | ((u64)(m.w != 0) << 3)) << ((lane & 15) * 4);
    v |= __shfl_xor(v, 1, 64);
    v |= __shfl_xor(v, 2, 64);
    v |= __shfl_xor(v, 4, 64);
    v |= __shfl_xor(v, 8, 64);
    if ((lane & 15) == 0) {
        mb[gw0] = v;
        if (v != ~0ull) atomicAnd(&diag[2], 0u);
    }
}

// ---------------------------------------------------------------------------
// Transpose INPUT weight (f32 or bf16 per flag) -> bf16: out[C x R] = in^T
// ---------------------------------------------------------------------------
__global__ __launch_bounds__(256) void transpose_in(
    const void* __restrict__ in, u16* __restrict__ out, int R, int C,
    const u32* __restrict__ diag)
{
    const int f32 = (int)diag[1];
    __shared__ u16 tile[32][33];
    int bx = blockIdx.x << 5;
    int by = blockIdx.y << 5;
    int tx = threadIdx.x & 31, ty = threadIdx.x >> 5;
    #pragma unroll
    for (int i = ty; i < 32; i += 8)
        tile[i][tx] = f2b(ldx(in, (size_t)(by + i) * C + bx + tx, f32));
    __syncthreads();
    #pragma unroll
    for (int i = ty; i < 32; i += 8) out[(size_t)(bx + i) * R + by + tx] = tile[tx][i];
}

// ---------------------------------------------------------------------------
// Four 1024x1024 weight transposes fused into one launch (blockIdx.z picks).
// ---------------------------------------------------------------------------
__global__ __launch_bounds__(256) void transpose4_in(
    const void* __restrict__ a0, const void* __restrict__ a1,
    const void* __restrict__ a2, const void* __restrict__ a3,
    u16* __restrict__ o0, u16* __restrict__ o1,
    u16* __restrict__ o2, u16* __restrict__ o3,
    const u32* __restrict__ diag)
{
    const int f32 = (int)diag[1];
    __shared__ u16 tile[32][33];
    const void* in; u16* out;
    switch (blockIdx.z) {
        case 0:  in = a0; out = o0; break;
        case 1:  in = a1; out = o1; break;
        case 2:  in = a2; out = o2; break;
        default: in = a3; out = o3; break;
    }
    int bx = blockIdx.x << 5;
    int by = blockIdx.y << 5;
    int tx = threadIdx.x & 31, ty = threadIdx.x >> 5;
    #pragma unroll
    for (int i = ty; i < 32; i += 8)
        tile[i][tx] = f2b(ldx(in, (size_t)(by + i) * 1024 + bx + tx, f32));
    __syncthreads();
    #pragma unroll
    for (int i = ty; i < 32; i += 8) out[(size_t)(bx + i) * 1024 + by + tx] = tile[tx][i];
}

// ---------------------------------------------------------------------------
// MFMA bf16 GEMM, C = (A(MxK) @ Bt(NxK)^T + bias) * scale. A always bf16.
// 128x128 tile, BK=32, 256 threads (4 waves x 64x64).
// R9: REVERTED to R5's 2-phase double-buffer (R8's depth-3 + sched_barrier
// pinning regressed ~20 us — m141 pattern). Added: XCD-chunked block remap
// (1-D grid; each XCD gets a contiguous by-major range -> B-panels L2-hit).
// Swizzle: pre-swizzled global source + swizzled fragment read (involution).
// MODE 1: bf16 -> (B,H,S,64); 2: bf16 -> (B,H,64,S); 3: bf16 row-major;
// MODE 4: bf16 relu row-major.
// ---------------------------------------------------------------------------
template<int MODE>
__global__ __launch_bounds__(256) void gemm_bt(
    const void* __restrict__ Av, const u16* __restrict__ Bt,
    const void* __restrict__ bias, u16* __restrict__ outp,
    int M, int N, int K, float scale, const u32* __restrict__ diag)
{
    __shared__ alignas(16) u16 lds_a[2][4096];
    __shared__ alignas(16) u16 lds_b[2][4096];
    const int bf32 = (int)diag[1];
    const int t = threadIdx.x;
    const int w = t >> 6, lane = t & 63;
    const int wm = (w >> 1) << 6, wn = (w & 1) << 6;
    const int ll = lane & 15, lh = lane >> 4;

    // XCD-chunked remap: grid is 1-D (nbx*nby, %8==0). Contiguous vids share
    // the same by (B panel) -> each XCD's L2 holds few panels instead of all.
    const int nbx = M >> 7;
    const int id = blockIdx.x;
    const int vid = (id & 7) * ((int)gridDim.x >> 3) + (id >> 3);
    const int bx = vid % nbx, by = vid / nbx;

    const size_t rowA = (size_t)bx * 128;
    const size_t rowB = (size_t)by * 128;
    const u16* aBase = (const u16*)Av + rowA * K;
    const u16* bBase = Bt + rowB * K;

    const int sr = w * 32 + (lane >> 2);                 // chunk-0 row
    const int sj = (lane & 3) ^ ((lane >> 3) & 3);       // (sr>>1)&3 == (lane>>3)&3
    const size_t gOff0 = (size_t)sr * K + sj * 8;
    const size_t gOff1 = (size_t)(sr + 16) * K + sj * 8;

    const int rdcol = (lh ^ ((ll >> 1) & 3)) * 8;

    f32x4 acc[4][4] = {};

#define STAGE(BUF, K0) do {                                                    \
        gload16(aBase + gOff0 + (K0), &lds_a[BUF][(w * 32) * 32]);             \
        gload16(aBase + gOff1 + (K0), &lds_a[BUF][(w * 32 + 16) * 32]);        \
        gload16(bBase + gOff0 + (K0), &lds_b[BUF][(w * 32) * 32]);             \
        gload16(bBase + gOff1 + (K0), &lds_b[BUF][(w * 32 + 16) * 32]);        \
    } while (0)

#define GCOMPUTE(BUF) do {                                                     \
        bf16x8 af[4], bfg[4];                                                  \
        _Pragma("unroll")                                                      \
        for (int tm = 0; tm < 4; tm++)                                         \
            af[tm]  = *(const bf16x8*)&lds_a[BUF][(wm + tm * 16 + ll) * 32 + rdcol]; \
        _Pragma("unroll")                                                      \
        for (int tn = 0; tn < 4; tn++)                                         \
            bfg[tn] = *(const bf16x8*)&lds_b[BUF][(wn + tn * 16 + ll) * 32 + rdcol]; \
        _Pragma("unroll")                                                      \
        for (int tm = 0; tm < 4; tm++)                                         \
            _Pragma("unroll")                                                  \
            for (int tn = 0; tn < 4; tn++)                                     \
                acc[tm][tn] = __builtin_amdgcn_mfma_f32_16x16x32_bf16(         \
                    af[tm], bfg[tn], acc[tm][tn], 0, 0, 0);                    \
    } while (0)

    STAGE(0, 0);
    __syncthreads();
    for (int k0 = 0; k0 < K; k0 += 64) {
        if (k0 + 32 < K) STAGE(1, k0 + 32);   // issue next tile BEFORE compute
        GCOMPUTE(0);
        __syncthreads();                       // drains vmcnt (next tile ready)
        if (k0 + 64 < K) STAGE(0, k0 + 64);
        GCOMPUTE(1);
        __syncthreads();
    }
#undef STAGE
#undef GCOMPUTE

    #pragma unroll
    for (int tm = 0; tm < 4; tm++)
    #pragma unroll
    for (int tn = 0; tn < 4; tn++)
    #pragma unroll
    for (int r = 0; r < 4; r++) {
        int gr = (int)rowA + wm + tm*16 + lh*4 + r;      // C row (M)
        int gc = (int)rowB + wn + tn*16 + ll;            // C col (N)
        float v = (acc[tm][tn][r] + ldx(bias, gc, bf32)) * scale;
        if (MODE == 1) {
            int b = gr >> 10, s = gr & 1023, h = gc >> 6, d = gc & 63;
            outp[((((size_t)(b*16 + h) << 10) | s) << 6) + d] = f2b(v);
        } else if (MODE == 2) {
            int b = gr >> 10, s = gr & 1023, h = gc >> 6, d = gc & 63;
            outp[((((size_t)(b*16 + h) << 6) | d) << 10) + s] = f2b(v);
        } else if (MODE == 3) {
            outp[(size_t)gr * N + gc] = f2b(v);
        } else {
            outp[(size_t)gr * N + gc] = f2b(fmaxf(v, 0.f));
        }
    }
}

// ---------------------------------------------------------------------------
// qr via MFMA: qr[row][rr] = q_scaled[row][:] . rel_k[rr][:]  (M=131072,
// N=33, K=64 GEMM). rel_k staged once as bf16 in LDS, rows 33..47 zeroed.
// ---------------------------------------------------------------------------
__global__ __launch_bounds__(256) void qr_mfma(
    const u16* __restrict__ q, const void* __restrict__ rel_k,
    u16* __restrict__ qr, const u32* __restrict__ diag)
{
    const int f32 = (int)diag[1];
    __shared__ alignas(16) u16 rk_lds[48 * 64];      // 6144 B
    int t = threadIdx.x;
    for (int i = t; i < 48 * 64; i += 256)
        rk_lds[i] = (i < 33 * 64) ? f2b(ldx(rel_k, i, f32)) : (u16)0;
    __syncthreads();

    const int lane = t & 63, w = t >> 6;
    const int ll = lane & 15, lh = lane >> 4;
    const size_t rowbase = (size_t)blockIdx.x * 256 + w * 64;

    f32x4 acc[4][3] = {};
    #pragma unroll
    for (int kk = 0; kk < 2; kk++) {
        bf16x8 bf[3];
        #pragma unroll
        for (int rt = 0; rt < 3; rt++)
            bf[rt] = *(const bf16x8*)&rk_lds[(rt * 16 + ll) * 64 + kk * 32 + lh * 8];
        #pragma unroll
        for (int tm = 0; tm < 4; tm++) {
            bf16x8 af = *(const bf16x8*)(q + (rowbase + tm * 16 + ll) * 64 + kk * 32 + lh * 8);
            #pragma unroll
            for (int rt = 0; rt < 3; rt++)
                acc[tm][rt] = __builtin_amdgcn_mfma_f32_16x16x32_bf16(
                    af, bf[rt], acc[tm][rt], 0, 0, 0);
        }
    }

    #pragma unroll
    for (int tm = 0; tm < 4; tm++)
    #pragma unroll
    for (int rt = 0; rt < 3; rt++) {
        int rr = rt * 16 + ll;
        if (rr < 33) {
            #pragma unroll
            for (int r = 0; r < 4; r++) {
                size_t row = rowbase + tm * 16 + lh * 4 + r;
                qr[row * 33 + rr] = f2b(acc[tm][rt][r]);
            }
        }
    }
}

// ---------------------------------------------------------------------------
// Fused relative attention — R5 structure (161 us measured; best).
// Raw lgkm-only barriers + named reg prefetch, qr in LDS, deferred lo/hi
// reduction, mask-free duplicated bodies, setprio, XCD remap.
// ---------------------------------------------------------------------------
#define SM_NEAR(MASKED)                                                        \
        _Pragma("unroll")                                                      \
        for (int tm = 0; tm < 4; tm++)                                         \
        _Pragma("unroll")                                                      \
        for (int r = 0; r < 4; r++) {                                          \
            int il = tm*16 + lh*4 + r;                                         \
            u64 bits = MASKED ? mrow[(size_t)il * 16 + kb] : ~0ull;            \
            int ig = qb*64 + il;                                               \
            float lo_p = 0.f, hi_p = 0.f;                                      \
            _Pragma("unroll")                                                  \
            for (int tn = 0; tn < 4; tn++) {                                   \
                int jl = tn*16 + ll;                                           \
                int d0 = kb*64 + jl - ig;                                      \
                int dd = (d0 < -16 ? -16 : (d0 > 16 ? 16 : d0)) + 16;          \
                float sc = sacc[tm][tn][r] + b2f(qr_lds[w][il][dd]);           \
                float pf = __expf(fminf(sc, 30.f));                            \
                if (MASKED) pf = ((bits >> jl) & 1ull) ? pf : 0.f;             \
                p_lds[w][il][jl] = f2b(pf);                                    \
                if (dd == 0) lo_p += pf;                                       \
                else if (dd == 32) hi_p += pf;                                 \
                else bandb[(size_t)il * 32 + dd - 1] = f2b(pf);                \
            }                                                                  \
            slo[tm*4 + r] += lo_p; shi[tm*4 + r] += hi_p;                      \
        }

#define SM_FAR(MASKED)                                                         \
        _Pragma("unroll")                                                      \
        for (int tm = 0; tm < 4; tm++)                                         \
        _Pragma("unroll")                                                      \
        for (int r = 0; r < 4; r++) {                                          \
            int il = tm*16 + lh*4 + r;                                         \
            u64 bits = MASKED ? mrow[(size_t)il * 16 + kb] : ~0ull;            \
            float qrv = b2f(qr_lds[w][il][sel]);                               \
            float part = 0.f;                                                  \
            _Pragma("unroll")                                                  \
            for (int tn = 0; tn < 4; tn++) {                                   \
                int jl = tn*16 + ll;                                           \
                float sc = sacc[tm][tn][r] + qrv;                              \
                float pf = __expf(fminf(sc, 30.f));                            \
                if (MASKED) pf = ((bits >> jl) & 1ull) ? pf : 0.f;             \
                p_lds[w][il][jl] = f2b(pf);                                    \
                part += pf;                                                    \
            }                                                                  \
            if (sel == 0) slo[tm*4 + r] += part; else shi[tm*4 + r] += part;   \
        }

__global__ __launch_bounds__(256) void attn_kernel(
    const u16* __restrict__ q, const u16* __restrict__ k, const u16* __restrict__ vT,
    const u16* __restrict__ qr, const u64* __restrict__ mbits,
    u16* __restrict__ band, float* __restrict__ lohi,
    u16* __restrict__ o, const u32* __restrict__ diag)
{
    __shared__ alignas(16) u16 k_lds[4096];
    __shared__ alignas(16) u16 v_lds[4096];
    __shared__ alignas(16) u16 p_lds[4][64][72];
    __shared__ alignas(16) u16 qr_lds[4][64][33];

    const int g  = blockIdx.x;
    const int vb = (g & 7) * 64 + (g >> 3);          // bijective on [0,512)
    const int bh = vb >> 2;
    const int w  = threadIdx.x >> 6;
    const int qb = ((vb & 3) << 2) + w;
    const int b = bh >> 4, hh = bh & 15;
    const int lane = threadIdx.x & 63;
    const int ll = lane & 15, lh = lane >> 4;
    const int t = threadIdx.x;
    const int allm = (int)diag[2];

    bf16x8 aq[4][2];
    const u16* qbase = q + ((size_t)bh * 1024 + qb * 64) * 64;
    #pragma unroll
    for (int tm = 0; tm < 4; tm++)
        #pragma unroll
        for (int kk = 0; kk < 2; kk++)
            aq[tm][kk] = *(const bf16x8*)(qbase + (size_t)(tm*16 + ll) * 64 + kk*32 + lh*8);

    const u16* qrb = qr + ((size_t)bh * 1024 + qb * 64) * 33;
    {
        const u32* srcq = (const u32*)qrb;
        u32* dstq = (u32*)&qr_lds[w][0][0];
        #pragma unroll
        for (int i = 0; i < 17; i++) {
            int idx = lane + (i << 6);
            if (idx < 1056) dstq[idx] = srcq[idx];
        }
    }

    f32x4 oacc[4][4] = {};
    float slo[16], shi[16];
    #pragma unroll
    for (int i = 0; i < 16; i++) { slo[i] = 0.f; shi[i] = 0.f; }

    const u16* kbase = k + (size_t)bh * 65536;
    const u16* vbase = vT + (size_t)bh * 65536;
    const u64* mrow = mbits + ((size_t)b * 1024 + qb * 64) * 16;
    u16* bandb = band + ((size_t)bh * 1024 + qb * 64) * 32;

    const int c0 = t, c1 = t + 256;
    const u16 *kp0, *kp1, *vp0, *vp1;
    {
        int tn = c0 >> 7, kk2 = (c0 >> 6) & 1, qd = (c0 >> 4) & 3, l2 = c0 & 15;
        kp0 = kbase + (size_t)(tn*16 + l2)*64 + kk2*32 + qd*8;
        vp0 = vbase + (size_t)(tn*16 + l2)*1024 + kk2*32 + qd*8;
    }
    {
        int tn = c1 >> 7, kk2 = (c1 >> 6) & 1, qd = (c1 >> 4) & 3, l2 = c1 & 15;
        kp1 = kbase + (size_t)(tn*16 + l2)*64 + kk2*32 + qd*8;
        vp1 = vbase + (size_t)(tn*16 + l2)*1024 + kk2*32 + qd*8;
    }
    bf16x8 pk0 = *(const bf16x8*)kp0;                // tile 0
    bf16x8 pk1 = *(const bf16x8*)kp1;
    bf16x8 pv0 = *(const bf16x8*)vp0;
    bf16x8 pv1 = *(const bf16x8*)vp1;

    for (int kb = 0; kb < 16; kb++) {
        asm volatile("s_waitcnt lgkmcnt(0)" ::: "memory");
        __builtin_amdgcn_s_barrier();
        *(bf16x8*)&k_lds[c0*8] = pk0;          // commit (compiler waits vmcnt)
        *(bf16x8*)&k_lds[c1*8] = pk1;
        *(bf16x8*)&v_lds[c0*8] = pv0;
        *(bf16x8*)&v_lds[c1*8] = pv1;
        if (kb < 15) {                         // issue t+1 loads; stay in flight
            pk0 = *(const bf16x8*)(kp0 + (size_t)(kb + 1) * 4096);
            pk1 = *(const bf16x8*)(kp1 + (size_t)(kb + 1) * 4096);
            pv0 = *(const bf16x8*)(vp0 + (size_t)(kb + 1) * 64);
            pv1 = *(const bf16x8*)(vp1 + (size_t)(kb + 1) * 64);
        }
        asm volatile("s_waitcnt lgkmcnt(0)" ::: "memory");
        __builtin_amdgcn_s_barrier();

        f32x4 sacc[4][4] = {};
        #pragma unroll
        for (int kk = 0; kk < 2; kk++) {
            bf16x8 bk[4];
            #pragma unroll
            for (int tn = 0; tn < 4; tn++)
                bk[tn] = *(const bf16x8*)&k_lds[(((tn*2 + kk) << 6) + lane) * 8];
            __builtin_amdgcn_s_setprio(1);
            #pragma unroll
            for (int tm = 0; tm < 4; tm++)
                #pragma unroll
                for (int tn = 0; tn < 4; tn++)
                    sacc[tm][tn] = __builtin_amdgcn_mfma_f32_16x16x32_bf16(
                        aq[tm][kk], bk[tn], sacc[tm][tn], 0, 0, 0);
            __builtin_amdgcn_s_setprio(0);
        }

        const int diff = kb - qb;
        const int sel = (diff < 0) ? 0 : 32;   // in scope for all expansions
        if (diff >= -1 && diff <= 1) {
            if (allm) { SM_NEAR(0) } else { SM_NEAR(1) }
        } else {
            if (allm) { SM_FAR(0) } else { SM_FAR(1) }
        }

        #pragma unroll
        for (int kk = 0; kk < 2; kk++) {
            bf16x8 ap[4], bv[4];
            #pragma unroll
            for (int tm = 0; tm < 4; tm++)
                ap[tm] = *(const bf16x8*)&p_lds[w][tm*16 + ll][kk*32 + lh*8];
            #pragma unroll
            for (int tn = 0; tn < 4; tn++)
                bv[tn] = *(const bf16x8*)&v_lds[(((tn*2 + kk) << 6) + lane) * 8];
            __builtin_amdgcn_s_setprio(1);
            #pragma unroll
            for (int tm = 0; tm < 4; tm++)
                #pragma unroll
                for (int tn = 0; tn < 4; tn++)
                    oacc[tm][tn] = __builtin_amdgcn_mfma_f32_16x16x32_bf16(
                        ap[tm], bv[tn], oacc[tm][tn], 0, 0, 0);
            __builtin_amdgcn_s_setprio(0);
        }
    }

    // deferred cross-lane (ll) reduction of lo/hi sums — once, not per tile
    #pragma unroll
    for (int i = 0; i < 16; i++) {
        float a = slo[i], c = shi[i];
        a += __shfl_xor(a, 1, 64); c += __shfl_xor(c, 1, 64);
        a += __shfl_xor(a, 2, 64); c += __shfl_xor(c, 2, 64);
        a += __shfl_xor(a, 4, 64); c += __shfl_xor(c, 4, 64);
        a += __shfl_xor(a, 8, 64); c += __shfl_xor(c, 8, 64);
        slo[i] = a; shi[i] = c;
    }

    if (ll == 0) {
        size_t row0 = (size_t)bh * 1024 + qb * 64;
        #pragma unroll
        for (int i = 0; i < 16; i++) {
            int il = (i >> 2)*16 + lh*4 + (i & 3);
            lohi[(row0 + il)*2]     = slo[i];
            lohi[(row0 + il)*2 + 1] = shi[i];
        }
    }

    #pragma unroll
    for (int tm = 0; tm < 4; tm++)
    #pragma unroll
    for (int tn = 0; tn < 4; tn++)
    #pragma unroll
    for (int r = 0; r < 4; r++) {
        int il = tm*16 + lh*4 + r;
        int d  = tn*16 + ll;
        int sg = qb*64 + il;
        o[((size_t)(b*1024 + sg)) * 1024 + hh*64 + d] = f2b(oacc[tm][tn][r]);
    }
}
#undef SM_NEAR
#undef SM_FAR

// ---------------------------------------------------------------------------
// Finisher: rebuild per-row buckets from band+lohi, o = (o_un + br@rel_v)/sum.
// ---------------------------------------------------------------------------
__global__ __launch_bounds__(256) void attn_fin(
    const u16* __restrict__ band, const float* __restrict__ lohi,
    const void* __restrict__ rel_v, u16* __restrict__ o, const u32* __restrict__ diag)
{
    __shared__ float rv[33][64];
    const int f32 = (int)diag[1];
    int t = threadIdx.x;
    for (int i = t; i < 33*64; i += 256) (&rv[0][0])[i] = ldx(rel_v, i, f32);
    __syncthreads();
    int d = t & 63;
    #pragma unroll
    for (int rg = 0; rg < 4; rg++) {
        int row = blockIdx.x * 16 + rg * 4 + (t >> 6);   // bh*1024 + s
        int s = row & 1023;
        const u64* bd8 = (const u64*)(band + (size_t)row * 32);
        u64 bq[4] = { bd8[0], bd8[1], bd8[2], bd8[3] };
        float lo = lohi[(size_t)row * 2], hi = lohi[(size_t)row * 2 + 1];
        float denom = lo + hi;
        float w2 = lo * rv[0][d] + hi * rv[32][d];
        #pragma unroll
        for (int dd = 1; dd < 32; dd++) {
            int j = s + dd - 16;
            if (j >= 0 && j < 1024) {
                u16 raw = (u16)(bq[(dd - 1) >> 2] >> (((dd - 1) & 3) * 16));
                float bv = b2f(raw);
                denom += bv;
                w2 += bv * rv[dd][d];
            }
        }
        int bb = row >> 14, h = (row >> 10) & 15;
        size_t idx = (size_t)(bb*1024 + s) * 1024 + h*64 + d;
        o[idx] = f2b((b2f(o[idx]) + w2) / denom);
    }
}

// ---------------------------------------------------------------------------
// out = LayerNorm(xa + xb) * g + b.  Vectorized: thread owns 4 contiguous
// elements (float4 / u64 loads, u64 packed store).
// ---------------------------------------------------------------------------
__global__ __launch_bounds__(256) void ln_kernel(
    const void* __restrict__ xa, int xa_ext, const u16* __restrict__ xb,
    const void* __restrict__ g, const void* __restrict__ bb,
    void* __restrict__ out, int final_out, const u32* __restrict__ diag)
{
    __shared__ float redS[4], redS2[4];
    const int inf32 = (int)diag[1];
    const int af32 = xa_ext ? inf32 : 0;
    const int of32 = final_out ? inf32 : 0;
    int row = blockIdx.x;
    int t = threadIdx.x;
    size_t base = (size_t)row << 10;
    int c0 = t * 4;
    float v[4]; float s = 0.f, s2 = 0.f;
    if (af32) {
        float4 a = *(const float4*)((const float*)xa + base + c0);
        v[0] = a.x; v[1] = a.y; v[2] = a.z; v[3] = a.w;
    } else {
        u64 xv = *(const u64*)((const u16*)xa + base + c0);
        v[0] = b2f((u16)xv);         v[1] = b2f((u16)(xv >> 16));
        v[2] = b2f((u16)(xv >> 32)); v[3] = b2f((u16)(xv >> 48));
    }
    {
        u64 bv_ = *(const u64*)(xb + base + c0);
        v[0] += b2f((u16)bv_);         v[1] += b2f((u16)(bv_ >> 16));
        v[2] += b2f((u16)(bv_ >> 32)); v[3] += b2f((u16)(bv_ >> 48));
    }
    #pragma unroll
    for (int i = 0; i < 4; i++) { s += v[i]; s2 += v[i] * v[i]; }
    #pragma unroll
    for (int off = 1; off < 64; off <<= 1) {
        s  += __shfl_xor(s,  off, 64);
        s2 += __shfl_xor(s2, off, 64);
    }
    int w = t >> 6;
    if ((t & 63) == 0) { redS[w] = s; redS2[w] = s2; }
    __syncthreads();
    float S  = redS[0] + redS[1] + redS[2] + redS[3];
    float S2 = redS2[0] + redS2[1] + redS2[2] + redS2[3];
    float mean = S * (1.f / 1024.f);
    float var  = S2 * (1.f / 1024.f) - mean * mean;
    float rstd = rsqrtf(var + 1e-5f);
    float gg[4], bv2[4];
    if (inf32) {
        float4 a = *(const float4*)((const float*)g + c0);
        float4 c = *(const float4*)((const float*)bb + c0);
        gg[0]=a.x; gg[1]=a.y; gg[2]=a.z; gg[3]=a.w;
        bv2[0]=c.x; bv2[1]=c.y; bv2[2]=c.z; bv2[3]=c.w;
    } else {
        u64 gv = *(const u64*)((const u16*)g + c0);
        u64 cv = *(const u64*)((const u16*)bb + c0);
        gg[0]=b2f((u16)gv); gg[1]=b2f((u16)(gv>>16)); gg[2]=b2f((u16)(gv>>32)); gg[3]=b2f((u16)(gv>>48));
        bv2[0]=b2f((u16)cv); bv2[1]=b2f((u16)(cv>>16)); bv2[2]=b2f((u16)(cv>>32)); bv2[3]=b2f((u16)(cv>>48));
    }
    float r[4];
    #pragma unroll
    for (int i = 0; i < 4; i++) r[i] = (v[i] - mean) * rstd * gg[i] + bv2[i];
    if (of32) {
        float4 ov; ov.x = r[0]; ov.y = r[1]; ov.z = r[2]; ov.w = r[3];
        *(float4*)((float*)out + base + c0) = ov;
    } else {
        u64 pv = (u64)f2b(r[0]) | ((u64)f2b(r[1]) << 16)
               | ((u64)f2b(r[2]) << 32) | ((u64)f2b(r[3]) << 48);
        *(u64*)((u16*)out + base + c0) = pv;
    }
}

// ---------------------------------------------------------------------------
extern "C" void kernel_launch(void* const* d_in, const int* in_sizes, int n_in,
                              void* d_out, int out_size, void* d_ws, size_t ws_size,
                              hipStream_t stream)
{
    (void)in_sizes; (void)n_in;
    const void* x     = d_in[0];
    const int*  mask  = (const int*)d_in[1];
    const void* wq    = d_in[2];
    const void* bq    = d_in[3];
    const void* wk    = d_in[4];
    const void* bk    = d_in[5];
    const void* wv    = d_in[6];
    const void* bv    = d_in[7];
    const void* wo    = d_in[8];
    const void* bo    = d_in[9];
    const void* rel_k = d_in[10];
    const void* rel_v = d_in[11];
    const void* fc1w  = d_in[12];
    const void* fc1b  = d_in[13];
    const void* fc2w  = d_in[14];
    const void* fc2b  = d_in[15];
    const void* ln1g  = d_in[16];
    const void* ln1b  = d_in[17];
    const void* ln2g  = d_in[18];
    const void* ln2b  = d_in[19];

    const size_t NEED = 117440768;   // 112 MiB (validated in round 4/5)
    if (ws_size < NEED) {
        float mb = -(float)(double)(ws_size >> 20);
        diag_fill_f32<<<dim3(2048), 256, 0, stream>>>((float*)d_out, mb, out_size);
        return;
    }

    // ws layout (bytes). diag never aliased.
    char* ws = (char*)d_ws;
    u32*   diag  = (u32*)  (ws + 0);            // 256 B
    u16*   fc1T  = (u16*)  (ws + 256);
    u16*   fc2T  = (u16*)  (ws + 8388864);
    u16*   woT   = (u16*)  (ws + 16777472);
    u16*   wqT   = (u16*)  (ws + 18874624);
    u16*   wkT   = (u16*)  (ws + 20971776);
    u16*   wvT   = (u16*)  (ws + 23068928);
    u16*   q_    = (u16*)  (ws + 25166080);
    u16*   k_    = (u16*)  (ws + 41943296);
    u16*   vT_   = (u16*)  (ws + 58720512);
    u16*   qr_   = (u16*)  (ws + 75497728);     // 8650752
    u16*   o_    = (u16*)  (ws + 84148480);     // ..100925696
    u16*   band_ = (u16*)  (ws + 100925696);    // 8388608 -> 109314304
    float* lohi_ = (float*)(ws + 109314304);    // 1048576 -> 110362880
    u64*   mb_   = (u64*)  (ws + 110362880);    // 1048576 -> 111411456
    u16*   xbf_  = (u16*)  (ws + 84148480);     // alias o_ (dead until attn writes it)
    u16*   ao_   = (u16*)  (ws + 58720512);     // alias vT_  [dead after attn]
    u16*   x1_   = (u16*)  (ws + 16777472);     // alias woT..q head [dead then]
    u16*   ff1   = (u16*)  (ws + 33554688);     // alias q tail,k,vT,qr,o [dead]
    u16*   ao2   = (u16*)  (ws + 100663552);    // alias band/lohi/mb [dead after fin]

    init_diag<<<dim3(1), 64, 0, stream>>>((const u16*)x, diag);
    xconv<<<dim3(4096), 256, 0, stream>>>(x, xbf_, diag);
    mask_bits_kernel<<<dim3(8192), 256, 0, stream>>>(mask, mb_, diag);

    transpose4_in<<<dim3(32, 32, 4), 256, 0, stream>>>(wq, wk, wv, wo,
                                                       wqT, wkT, wvT, woT, diag);
    transpose_in<<<dim3(128, 32), 256, 0, stream>>>(fc1w, fc1T, 1024, 4096, diag);
    transpose_in<<<dim3(32, 128), 256, 0, stream>>>(fc2w, fc2T, 4096, 1024, diag);

    // q pre-scaled by 1/sqrt(HD)=0.125 (exact in bf16); qr inherits the scale
    gemm_bt<1><<<dim3(512), 256, 0, stream>>>(xbf_, wqT, bq, q_,  8192, 1024, 1024, 0.125f, diag);
    gemm_bt<1><<<dim3(512), 256, 0, stream>>>(xbf_, wkT, bk, k_,  8192, 1024, 1024, 1.0f, diag);
    gemm_bt<2><<<dim3(512), 256, 0, stream>>>(xbf_, wvT, bv, vT_, 8192, 1024, 1024, 1.0f, diag);

    qr_mfma<<<dim3(512), 256, 0, stream>>>(q_, rel_k, qr_, diag);
    attn_kernel<<<dim3(512), 256, 0, stream>>>(q_, k_, vT_, qr_, mb_, band_, lohi_, o_, diag);
    attn_fin<<<dim3(8192), 256, 0, stream>>>(band_, lohi_, rel_v, o_, diag);

    gemm_bt<3><<<dim3(512), 256, 0, stream>>>(o_, woT, bo, ao_, 8192, 1024, 1024, 1.0f, diag);
    ln_kernel<<<dim3(8192), 256, 0, stream>>>(x, 1, ao_, ln1g, ln1b, x1_, 0, diag);
    gemm_bt<4><<<dim3(2048), 256, 0, stream>>>(x1_, fc1T, fc1b, ff1, 8192, 4096, 1024, 1.0f, diag);
    gemm_bt<3><<<dim3(512), 256, 0, stream>>>(ff1, fc2T, fc2b, ao2, 8192, 1024, 4096, 1.0f, diag);
    ln_kernel<<<dim3(8192), 256, 0, stream>>>(x1_, 0, ao2, ln2g, ln2b, d_out, 1, diag);
}

// Round 10
// 728.060 us; speedup vs baseline: 1.0697x; 1.0697x over previous
//
#include <hip/hip_runtime.h>

typedef unsigned short u16;
typedef unsigned int   u32;
typedef unsigned long long u64;
using bf16x8 = __attribute__((ext_vector_type(8))) short;
using f32x4  = __attribute__((ext_vector_type(4))) float;

__device__ __forceinline__ float b2f(u16 u) {
    union { unsigned int i; float f; } x; x.i = ((unsigned int)u) << 16; return x.f;
}
__device__ __forceinline__ u16 f2b(float f) {
    union { float f; unsigned int i; } x; x.f = f;
    unsigned int i = x.i;
    return (u16)((i + 0x7FFFu + ((i >> 16) & 1u)) >> 16);  // RNE, inputs never NaN
}
// flag-aware scalar load of an INPUT tensor element (f32 or bf16 storage)
__device__ __forceinline__ float ldx(const void* p, size_t i, int f32) {
    return f32 ? ((const float*)p)[i] : b2f(((const u16*)p)[i]);
}
// async global->LDS, 16B per lane; lptr must be wave-uniform (HW: base+lane*16)
__device__ __forceinline__ void gload16(const void* g, void* l) {
    __builtin_amdgcn_global_load_lds(
        (const __attribute__((address_space(1))) void*)g,
        (__attribute__((address_space(3))) void*)l, 16, 0, 0);
}

// ---------------------------------------------------------------------------
// init_diag: diag[1] = inputs-are-f32 flag; diag[2] = mask-all-ones (refined
// by mask_bits_kernel).
// ---------------------------------------------------------------------------
__global__ __launch_bounds__(64) void init_diag(const u16* __restrict__ x, u32* diag)
{
    int lane = threadIdx.x;
    u16 v = x[lane * 2];
    int e = (v >> 7) & 0xFF;
    bool extreme = (e < 100) | (e > 154);
    u64 m = __ballot(extreme);
    if (lane == 0) { diag[0] = 0u; diag[1] = (m != 0ull) ? 1u : 0u; diag[2] = 1u; }
}

__global__ __launch_bounds__(256) void diag_fill_f32(float* __restrict__ out, float val, int n)
{
    for (int i = blockIdx.x * 256 + threadIdx.x; i < n; i += gridDim.x * 256) out[i] = val;
}

// ---------------------------------------------------------------------------
// xconv: x (f32 or bf16 per flag) -> contiguous bf16 copy.
// ---------------------------------------------------------------------------
__global__ __launch_bounds__(256) void xconv(
    const void* __restrict__ x, u16* __restrict__ xb, const u32* __restrict__ diag)
{
    const int f32 = (int)diag[1];
    size_t i0 = ((size_t)blockIdx.x * 256 + threadIdx.x) * 8;
    if (f32) {
        const float4* p = (const float4*)((const float*)x + i0);
        float4 a = p[0], b = p[1];
        bf16x8 v;
        v[0]=(short)f2b(a.x); v[1]=(short)f2b(a.y); v[2]=(short)f2b(a.z); v[3]=(short)f2b(a.w);
        v[4]=(short)f2b(b.x); v[5]=(short)f2b(b.y); v[6]=(short)f2b(b.z); v[7]=(short)f2b(b.w);
        *(bf16x8*)(xb + i0) = v;
    } else {
        *(bf16x8*)(xb + i0) = *(const bf16x8*)((const u16*)x + i0);
    }
}

// ---------------------------------------------------------------------------
// mask -> bitmask. 4 ints per thread (int4), shfl-OR pack — 8192 blocks.
// mb[gw] bit j = mask[gw*64 + j] != 0   (gw = (b*1024+i)*16 + w).
// ---------------------------------------------------------------------------
__global__ __launch_bounds__(256) void mask_bits_kernel(
    const int* __restrict__ mask, u64* __restrict__ mb, u32* __restrict__ diag)
{
    int t = threadIdx.x;
    int lane = t & 63, wv = t >> 6;
    int gw0 = blockIdx.x * 16 + wv * 4 + (lane >> 4);    // this lane's u64 word
    const int4* p = (const int4*)(mask + (size_t)gw0 * 64 + (lane & 15) * 4);
    int4 m = *p;
    u64 v = ((u64)(m.x != 0)      | ((u64)(m.y != 0) << 1)
           | ((u64)(m.z != 0) << 2) | ((u64)(m.w != 0) << 3)) << ((lane & 15) * 4);
    v |= __shfl_xor(v, 1, 64);
    v |= __shfl_xor(v, 2, 64);
    v |= __shfl_xor(v, 4, 64);
    v |= __shfl_xor(v, 8, 64);
    if ((lane & 15) == 0) {
        mb[gw0] = v;
        if (v != ~0ull) atomicAnd(&diag[2], 0u);
    }
}

// ---------------------------------------------------------------------------
// Transpose INPUT weight (f32 or bf16 per flag) -> bf16: out[C x R] = in^T
// ---------------------------------------------------------------------------
__global__ __launch_bounds__(256) void transpose_in(
    const void* __restrict__ in, u16* __restrict__ out, int R, int C,
    const u32* __restrict__ diag)
{
    const int f32 = (int)diag[1];
    __shared__ u16 tile[32][33];
    int bx = blockIdx.x << 5;
    int by = blockIdx.y << 5;
    int tx = threadIdx.x & 31, ty = threadIdx.x >> 5;
    #pragma unroll
    for (int i = ty; i < 32; i += 8)
        tile[i][tx] = f2b(ldx(in, (size_t)(by + i) * C + bx + tx, f32));
    __syncthreads();
    #pragma unroll
    for (int i = ty; i < 32; i += 8) out[(size_t)(bx + i) * R + by + tx] = tile[tx][i];
}

// ---------------------------------------------------------------------------
// Four 1024x1024 weight transposes fused into one launch (blockIdx.z picks).
// ---------------------------------------------------------------------------
__global__ __launch_bounds__(256) void transpose4_in(
    const void* __restrict__ a0, const void* __restrict__ a1,
    const void* __restrict__ a2, const void* __restrict__ a3,
    u16* __restrict__ o0, u16* __restrict__ o1,
    u16* __restrict__ o2, u16* __restrict__ o3,
    const u32* __restrict__ diag)
{
    const int f32 = (int)diag[1];
    __shared__ u16 tile[32][33];
    const void* in; u16* out;
    switch (blockIdx.z) {
        case 0:  in = a0; out = o0; break;
        case 1:  in = a1; out = o1; break;
        case 2:  in = a2; out = o2; break;
        default: in = a3; out = o3; break;
    }
    int bx = blockIdx.x << 5;
    int by = blockIdx.y << 5;
    int tx = threadIdx.x & 31, ty = threadIdx.x >> 5;
    #pragma unroll
    for (int i = ty; i < 32; i += 8)
        tile[i][tx] = f2b(ldx(in, (size_t)(by + i) * 1024 + bx + tx, f32));
    __syncthreads();
    #pragma unroll
    for (int i = ty; i < 32; i += 8) out[(size_t)(bx + i) * 1024 + by + tx] = tile[tx][i];
}

// ---------------------------------------------------------------------------
// MFMA bf16 GEMM, C = (A(MxK) @ Bt(NxK)^T + bias) * scale. A always bf16.
// 128x128 tile, BK=32, 256 threads (4 waves x 64x64).
// R10: reverted to R5's exact 2-phase double-buffer + 2-D grid (the config
// inside the 755.9 us measurement). R9's XCD-chunked remap regressed ~20 us:
// it gave each XCD one by-range (B locality) but made every XCD stream the
// ENTIRE A matrix (A-traffic dominates; default round-robin spreads A).
// Swizzle: pre-swizzled global source + swizzled fragment read (involution).
// MODE 1: bf16 -> (B,H,S,64); 2: bf16 -> (B,H,64,S); 3: bf16 row-major;
// MODE 4: bf16 relu row-major.
// ---------------------------------------------------------------------------
template<int MODE>
__global__ __launch_bounds__(256) void gemm_bt(
    const void* __restrict__ Av, const u16* __restrict__ Bt,
    const void* __restrict__ bias, u16* __restrict__ outp,
    int M, int N, int K, float scale, const u32* __restrict__ diag)
{
    __shared__ alignas(16) u16 lds_a[2][4096];
    __shared__ alignas(16) u16 lds_b[2][4096];
    const int bf32 = (int)diag[1];
    const int t = threadIdx.x;
    const int w = t >> 6, lane = t & 63;
    const int wm = (w >> 1) << 6, wn = (w & 1) << 6;
    const int ll = lane & 15, lh = lane >> 4;

    const size_t rowA = (size_t)blockIdx.x * 128;
    const size_t rowB = (size_t)blockIdx.y * 128;
    const u16* aBase = (const u16*)Av + rowA * K;
    const u16* bBase = Bt + rowB * K;

    const int sr = w * 32 + (lane >> 2);                 // chunk-0 row
    const int sj = (lane & 3) ^ ((lane >> 3) & 3);       // (sr>>1)&3 == (lane>>3)&3
    const size_t gOff0 = (size_t)sr * K + sj * 8;
    const size_t gOff1 = (size_t)(sr + 16) * K + sj * 8;

    const int rdcol = (lh ^ ((ll >> 1) & 3)) * 8;

    f32x4 acc[4][4] = {};

#define STAGE(BUF, K0) do {                                                    \
        gload16(aBase + gOff0 + (K0), &lds_a[BUF][(w * 32) * 32]);             \
        gload16(aBase + gOff1 + (K0), &lds_a[BUF][(w * 32 + 16) * 32]);        \
        gload16(bBase + gOff0 + (K0), &lds_b[BUF][(w * 32) * 32]);             \
        gload16(bBase + gOff1 + (K0), &lds_b[BUF][(w * 32 + 16) * 32]);        \
    } while (0)

#define GCOMPUTE(BUF) do {                                                     \
        bf16x8 af[4], bfg[4];                                                  \
        _Pragma("unroll")                                                      \
        for (int tm = 0; tm < 4; tm++)                                         \
            af[tm]  = *(const bf16x8*)&lds_a[BUF][(wm + tm * 16 + ll) * 32 + rdcol]; \
        _Pragma("unroll")                                                      \
        for (int tn = 0; tn < 4; tn++)                                         \
            bfg[tn] = *(const bf16x8*)&lds_b[BUF][(wn + tn * 16 + ll) * 32 + rdcol]; \
        _Pragma("unroll")                                                      \
        for (int tm = 0; tm < 4; tm++)                                         \
            _Pragma("unroll")                                                  \
            for (int tn = 0; tn < 4; tn++)                                     \
                acc[tm][tn] = __builtin_amdgcn_mfma_f32_16x16x32_bf16(         \
                    af[tm], bfg[tn], acc[tm][tn], 0, 0, 0);                    \
    } while (0)

    STAGE(0, 0);
    __syncthreads();
    for (int k0 = 0; k0 < K; k0 += 64) {
        if (k0 + 32 < K) STAGE(1, k0 + 32);   // issue next tile BEFORE compute
        GCOMPUTE(0);
        __syncthreads();                       // drains vmcnt (next tile ready)
        if (k0 + 64 < K) STAGE(0, k0 + 64);
        GCOMPUTE(1);
        __syncthreads();
    }
#undef STAGE
#undef GCOMPUTE

    #pragma unroll
    for (int tm = 0; tm < 4; tm++)
    #pragma unroll
    for (int tn = 0; tn < 4; tn++)
    #pragma unroll
    for (int r = 0; r < 4; r++) {
        int gr = (int)rowA + wm + tm*16 + lh*4 + r;      // C row (M)
        int gc = (int)rowB + wn + tn*16 + ll;            // C col (N)
        float v = (acc[tm][tn][r] + ldx(bias, gc, bf32)) * scale;
        if (MODE == 1) {
            int b = gr >> 10, s = gr & 1023, h = gc >> 6, d = gc & 63;
            outp[((((size_t)(b*16 + h) << 10) | s) << 6) + d] = f2b(v);
        } else if (MODE == 2) {
            int b = gr >> 10, s = gr & 1023, h = gc >> 6, d = gc & 63;
            outp[((((size_t)(b*16 + h) << 6) | d) << 10) + s] = f2b(v);
        } else if (MODE == 3) {
            outp[(size_t)gr * N + gc] = f2b(v);
        } else {
            outp[(size_t)gr * N + gc] = f2b(fmaxf(v, 0.f));
        }
    }
}

// ---------------------------------------------------------------------------
// R10: fused QKV GEMM. wqT/wkT/wvT are contiguous in ws -> B is one
// 3072x1024 matrix. which = by>>3 (block-uniform) selects bias, scale and
// output layout: q,k -> (B,H,S,64) [q scaled 0.125]; v -> (B,H,64,S).
// Same 2-phase body as gemm_bt. Grid dim3(64, 24).
// ---------------------------------------------------------------------------
__global__ __launch_bounds__(256) void gemm_qkv(
    const u16* __restrict__ Av, const u16* __restrict__ Bt,
    const void* __restrict__ bq, const void* __restrict__ bk,
    const void* __restrict__ bv,
    u16* __restrict__ qo, u16* __restrict__ ko, u16* __restrict__ vo,
    const u32* __restrict__ diag)
{
    const int K = 1024;
    __shared__ alignas(16) u16 lds_a[2][4096];
    __shared__ alignas(16) u16 lds_b[2][4096];
    const int bf32 = (int)diag[1];
    const int t = threadIdx.x;
    const int w = t >> 6, lane = t & 63;
    const int wm = (w >> 1) << 6, wn = (w & 1) << 6;
    const int ll = lane & 15, lh = lane >> 4;

    const size_t rowA = (size_t)blockIdx.x * 128;
    const size_t rowB = (size_t)blockIdx.y * 128;
    const u16* aBase = (const u16*)Av + rowA * K;
    const u16* bBase = Bt + rowB * K;

    const int which = (int)(blockIdx.y >> 3);            // 0=q,1=k,2=v
    const float scale = (which == 0) ? 0.125f : 1.0f;
    const void* bias = (which == 0) ? bq : ((which == 1) ? bk : bv);
    u16* outqk = (which == 0) ? qo : ko;

    const int sr = w * 32 + (lane >> 2);
    const int sj = (lane & 3) ^ ((lane >> 3) & 3);
    const size_t gOff0 = (size_t)sr * K + sj * 8;
    const size_t gOff1 = (size_t)(sr + 16) * K + sj * 8;

    const int rdcol = (lh ^ ((ll >> 1) & 3)) * 8;

    f32x4 acc[4][4] = {};

#define STAGE(BUF, K0) do {                                                    \
        gload16(aBase + gOff0 + (K0), &lds_a[BUF][(w * 32) * 32]);             \
        gload16(aBase + gOff1 + (K0), &lds_a[BUF][(w * 32 + 16) * 32]);        \
        gload16(bBase + gOff0 + (K0), &lds_b[BUF][(w * 32) * 32]);             \
        gload16(bBase + gOff1 + (K0), &lds_b[BUF][(w * 32 + 16) * 32]);        \
    } while (0)

#define GCOMPUTE(BUF) do {                                                     \
        bf16x8 af[4], bfg[4];                                                  \
        _Pragma("unroll")                                                      \
        for (int tm = 0; tm < 4; tm++)                                         \
            af[tm]  = *(const bf16x8*)&lds_a[BUF][(wm + tm * 16 + ll) * 32 + rdcol]; \
        _Pragma("unroll")                                                      \
        for (int tn = 0; tn < 4; tn++)                                         \
            bfg[tn] = *(const bf16x8*)&lds_b[BUF][(wn + tn * 16 + ll) * 32 + rdcol]; \
        _Pragma("unroll")                                                      \
        for (int tm = 0; tm < 4; tm++)                                         \
            _Pragma("unroll")                                                  \
            for (int tn = 0; tn < 4; tn++)                                     \
                acc[tm][tn] = __builtin_amdgcn_mfma_f32_16x16x32_bf16(         \
                    af[tm], bfg[tn], acc[tm][tn], 0, 0, 0);                    \
    } while (0)

    STAGE(0, 0);
    __syncthreads();
    for (int k0 = 0; k0 < K; k0 += 64) {
        if (k0 + 32 < K) STAGE(1, k0 + 32);
        GCOMPUTE(0);
        __syncthreads();
        if (k0 + 64 < K) STAGE(0, k0 + 64);
        GCOMPUTE(1);
        __syncthreads();
    }
#undef STAGE
#undef GCOMPUTE

    #pragma unroll
    for (int tm = 0; tm < 4; tm++)
    #pragma unroll
    for (int tn = 0; tn < 4; tn++)
    #pragma unroll
    for (int r = 0; r < 4; r++) {
        int gr = (int)rowA + wm + tm*16 + lh*4 + r;      // row in [0,8192)
        int gc = (int)rowB + wn + tn*16 + ll;            // col in [0,3072)
        int gcl = gc & 1023;
        float v = (acc[tm][tn][r] + ldx(bias, gcl, bf32)) * scale;
        int b = gr >> 10, s = gr & 1023, h = gcl >> 6, d = gcl & 63;
        if (which != 2)
            outqk[((((size_t)(b*16 + h) << 10) | s) << 6) + d] = f2b(v);
        else
            vo[((((size_t)(b*16 + h) << 6) | d) << 10) + s] = f2b(v);
    }
}

// ---------------------------------------------------------------------------
// qr via MFMA: qr[row][rr] = q_scaled[row][:] . rel_k[rr][:]  (M=131072,
// N=33, K=64 GEMM). rel_k staged once as bf16 in LDS, rows 33..47 zeroed.
// ---------------------------------------------------------------------------
__global__ __launch_bounds__(256) void qr_mfma(
    const u16* __restrict__ q, const void* __restrict__ rel_k,
    u16* __restrict__ qr, const u32* __restrict__ diag)
{
    const int f32 = (int)diag[1];
    __shared__ alignas(16) u16 rk_lds[48 * 64];      // 6144 B
    int t = threadIdx.x;
    for (int i = t; i < 48 * 64; i += 256)
        rk_lds[i] = (i < 33 * 64) ? f2b(ldx(rel_k, i, f32)) : (u16)0;
    __syncthreads();

    const int lane = t & 63, w = t >> 6;
    const int ll = lane & 15, lh = lane >> 4;
    const size_t rowbase = (size_t)blockIdx.x * 256 + w * 64;

    f32x4 acc[4][3] = {};
    #pragma unroll
    for (int kk = 0; kk < 2; kk++) {
        bf16x8 bf[3];
        #pragma unroll
        for (int rt = 0; rt < 3; rt++)
            bf[rt] = *(const bf16x8*)&rk_lds[(rt * 16 + ll) * 64 + kk * 32 + lh * 8];
        #pragma unroll
        for (int tm = 0; tm < 4; tm++) {
            bf16x8 af = *(const bf16x8*)(q + (rowbase + tm * 16 + ll) * 64 + kk * 32 + lh * 8);
            #pragma unroll
            for (int rt = 0; rt < 3; rt++)
                acc[tm][rt] = __builtin_amdgcn_mfma_f32_16x16x32_bf16(
                    af, bf[rt], acc[tm][rt], 0, 0, 0);
        }
    }

    #pragma unroll
    for (int tm = 0; tm < 4; tm++)
    #pragma unroll
    for (int rt = 0; rt < 3; rt++) {
        int rr = rt * 16 + ll;
        if (rr < 33) {
            #pragma unroll
            for (int r = 0; r < 4; r++) {
                size_t row = rowbase + tm * 16 + lh * 4 + r;
                qr[row * 33 + rr] = f2b(acc[tm][rt][r]);
            }
        }
    }
}

// ---------------------------------------------------------------------------
// Fused relative attention — R5 structure (161 us measured; best).
// Raw lgkm-only barriers + named reg prefetch, qr in LDS, deferred lo/hi
// reduction, mask-free duplicated bodies, setprio, XCD remap.
// ---------------------------------------------------------------------------
#define SM_NEAR(MASKED)                                                        \
        _Pragma("unroll")                                                      \
        for (int tm = 0; tm < 4; tm++)                                         \
        _Pragma("unroll")                                                      \
        for (int r = 0; r < 4; r++) {                                          \
            int il = tm*16 + lh*4 + r;                                         \
            u64 bits = MASKED ? mrow[(size_t)il * 16 + kb] : ~0ull;            \
            int ig = qb*64 + il;                                               \
            float lo_p = 0.f, hi_p = 0.f;                                      \
            _Pragma("unroll")                                                  \
            for (int tn = 0; tn < 4; tn++) {                                   \
                int jl = tn*16 + ll;                                           \
                int d0 = kb*64 + jl - ig;                                      \
                int dd = (d0 < -16 ? -16 : (d0 > 16 ? 16 : d0)) + 16;          \
                float sc = sacc[tm][tn][r] + b2f(qr_lds[w][il][dd]);           \
                float pf = __expf(fminf(sc, 30.f));                            \
                if (MASKED) pf = ((bits >> jl) & 1ull) ? pf : 0.f;             \
                p_lds[w][il][jl] = f2b(pf);                                    \
                if (dd == 0) lo_p += pf;                                       \
                else if (dd == 32) hi_p += pf;                                 \
                else bandb[(size_t)il * 32 + dd - 1] = f2b(pf);                \
            }                                                                  \
            slo[tm*4 + r] += lo_p; shi[tm*4 + r] += hi_p;                      \
        }

#define SM_FAR(MASKED)                                                         \
        _Pragma("unroll")                                                      \
        for (int tm = 0; tm < 4; tm++)                                         \
        _Pragma("unroll")                                                      \
        for (int r = 0; r < 4; r++) {                                          \
            int il = tm*16 + lh*4 + r;                                         \
            u64 bits = MASKED ? mrow[(size_t)il * 16 + kb] : ~0ull;            \
            float qrv = b2f(qr_lds[w][il][sel]);                               \
            float part = 0.f;                                                  \
            _Pragma("unroll")                                                  \
            for (int tn = 0; tn < 4; tn++) {                                   \
                int jl = tn*16 + ll;                                           \
                float sc = sacc[tm][tn][r] + qrv;                              \
                float pf = __expf(fminf(sc, 30.f));                            \
                if (MASKED) pf = ((bits >> jl) & 1ull) ? pf : 0.f;             \
                p_lds[w][il][jl] = f2b(pf);                                    \
                part += pf;                                                    \
            }                                                                  \
            if (sel == 0) slo[tm*4 + r] += part; else shi[tm*4 + r] += part;   \
        }

__global__ __launch_bounds__(256) void attn_kernel(
    const u16* __restrict__ q, const u16* __restrict__ k, const u16* __restrict__ vT,
    const u16* __restrict__ qr, const u64* __restrict__ mbits,
    u16* __restrict__ band, float* __restrict__ lohi,
    u16* __restrict__ o, const u32* __restrict__ diag)
{
    __shared__ alignas(16) u16 k_lds[4096];
    __shared__ alignas(16) u16 v_lds[4096];
    __shared__ alignas(16) u16 p_lds[4][64][72];
    __shared__ alignas(16) u16 qr_lds[4][64][33];

    const int g  = blockIdx.x;
    const int vb = (g & 7) * 64 + (g >> 3);          // bijective on [0,512)
    const int bh = vb >> 2;
    const int w  = threadIdx.x >> 6;
    const int qb = ((vb & 3) << 2) + w;
    const int b = bh >> 4, hh = bh & 15;
    const int lane = threadIdx.x & 63;
    const int ll = lane & 15, lh = lane >> 4;
    const int t = threadIdx.x;
    const int allm = (int)diag[2];

    bf16x8 aq[4][2];
    const u16* qbase = q + ((size_t)bh * 1024 + qb * 64) * 64;
    #pragma unroll
    for (int tm = 0; tm < 4; tm++)
        #pragma unroll
        for (int kk = 0; kk < 2; kk++)
            aq[tm][kk] = *(const bf16x8*)(qbase + (size_t)(tm*16 + ll) * 64 + kk*32 + lh*8);

    const u16* qrb = qr + ((size_t)bh * 1024 + qb * 64) * 33;
    {
        const u32* srcq = (const u32*)qrb;
        u32* dstq = (u32*)&qr_lds[w][0][0];
        #pragma unroll
        for (int i = 0; i < 17; i++) {
            int idx = lane + (i << 6);
            if (idx < 1056) dstq[idx] = srcq[idx];
        }
    }

    f32x4 oacc[4][4] = {};
    float slo[16], shi[16];
    #pragma unroll
    for (int i = 0; i < 16; i++) { slo[i] = 0.f; shi[i] = 0.f; }

    const u16* kbase = k + (size_t)bh * 65536;
    const u16* vbase = vT + (size_t)bh * 65536;
    const u64* mrow = mbits + ((size_t)b * 1024 + qb * 64) * 16;
    u16* bandb = band + ((size_t)bh * 1024 + qb * 64) * 32;

    const int c0 = t, c1 = t + 256;
    const u16 *kp0, *kp1, *vp0, *vp1;
    {
        int tn = c0 >> 7, kk2 = (c0 >> 6) & 1, qd = (c0 >> 4) & 3, l2 = c0 & 15;
        kp0 = kbase + (size_t)(tn*16 + l2)*64 + kk2*32 + qd*8;
        vp0 = vbase + (size_t)(tn*16 + l2)*1024 + kk2*32 + qd*8;
    }
    {
        int tn = c1 >> 7, kk2 = (c1 >> 6) & 1, qd = (c1 >> 4) & 3, l2 = c1 & 15;
        kp1 = kbase + (size_t)(tn*16 + l2)*64 + kk2*32 + qd*8;
        vp1 = vbase + (size_t)(tn*16 + l2)*1024 + kk2*32 + qd*8;
    }
    bf16x8 pk0 = *(const bf16x8*)kp0;                // tile 0
    bf16x8 pk1 = *(const bf16x8*)kp1;
    bf16x8 pv0 = *(const bf16x8*)vp0;
    bf16x8 pv1 = *(const bf16x8*)vp1;

    for (int kb = 0; kb < 16; kb++) {
        asm volatile("s_waitcnt lgkmcnt(0)" ::: "memory");
        __builtin_amdgcn_s_barrier();
        *(bf16x8*)&k_lds[c0*8] = pk0;          // commit (compiler waits vmcnt)
        *(bf16x8*)&k_lds[c1*8] = pk1;
        *(bf16x8*)&v_lds[c0*8] = pv0;
        *(bf16x8*)&v_lds[c1*8] = pv1;
        if (kb < 15) {                         // issue t+1 loads; stay in flight
            pk0 = *(const bf16x8*)(kp0 + (size_t)(kb + 1) * 4096);
            pk1 = *(const bf16x8*)(kp1 + (size_t)(kb + 1) * 4096);
            pv0 = *(const bf16x8*)(vp0 + (size_t)(kb + 1) * 64);
            pv1 = *(const bf16x8*)(vp1 + (size_t)(kb + 1) * 64);
        }
        asm volatile("s_waitcnt lgkmcnt(0)" ::: "memory");
        __builtin_amdgcn_s_barrier();

        f32x4 sacc[4][4] = {};
        #pragma unroll
        for (int kk = 0; kk < 2; kk++) {
            bf16x8 bk[4];
            #pragma unroll
            for (int tn = 0; tn < 4; tn++)
                bk[tn] = *(const bf16x8*)&k_lds[(((tn*2 + kk) << 6) + lane) * 8];
            __builtin_amdgcn_s_setprio(1);
            #pragma unroll
            for (int tm = 0; tm < 4; tm++)
                #pragma unroll
                for (int tn = 0; tn < 4; tn++)
                    sacc[tm][tn] = __builtin_amdgcn_mfma_f32_16x16x32_bf16(
                        aq[tm][kk], bk[tn], sacc[tm][tn], 0, 0, 0);
            __builtin_amdgcn_s_setprio(0);
        }

        const int diff = kb - qb;
        const int sel = (diff < 0) ? 0 : 32;   // in scope for all expansions
        if (diff >= -1 && diff <= 1) {
            if (allm) { SM_NEAR(0) } else { SM_NEAR(1) }
        } else {
            if (allm) { SM_FAR(0) } else { SM_FAR(1) }
        }

        #pragma unroll
        for (int kk = 0; kk < 2; kk++) {
            bf16x8 ap[4], bv[4];
            #pragma unroll
            for (int tm = 0; tm < 4; tm++)
                ap[tm] = *(const bf16x8*)&p_lds[w][tm*16 + ll][kk*32 + lh*8];
            #pragma unroll
            for (int tn = 0; tn < 4; tn++)
                bv[tn] = *(const bf16x8*)&v_lds[(((tn*2 + kk) << 6) + lane) * 8];
            __builtin_amdgcn_s_setprio(1);
            #pragma unroll
            for (int tm = 0; tm < 4; tm++)
                #pragma unroll
                for (int tn = 0; tn < 4; tn++)
                    oacc[tm][tn] = __builtin_amdgcn_mfma_f32_16x16x32_bf16(
                        ap[tm], bv[tn], oacc[tm][tn], 0, 0, 0);
            __builtin_amdgcn_s_setprio(0);
        }
    }

    // deferred cross-lane (ll) reduction of lo/hi sums — once, not per tile
    #pragma unroll
    for (int i = 0; i < 16; i++) {
        float a = slo[i], c = shi[i];
        a += __shfl_xor(a, 1, 64); c += __shfl_xor(c, 1, 64);
        a += __shfl_xor(a, 2, 64); c += __shfl_xor(c, 2, 64);
        a += __shfl_xor(a, 4, 64); c += __shfl_xor(c, 4, 64);
        a += __shfl_xor(a, 8, 64); c += __shfl_xor(c, 8, 64);
        slo[i] = a; shi[i] = c;
    }

    if (ll == 0) {
        size_t row0 = (size_t)bh * 1024 + qb * 64;
        #pragma unroll
        for (int i = 0; i < 16; i++) {
            int il = (i >> 2)*16 + lh*4 + (i & 3);
            lohi[(row0 + il)*2]     = slo[i];
            lohi[(row0 + il)*2 + 1] = shi[i];
        }
    }

    #pragma unroll
    for (int tm = 0; tm < 4; tm++)
    #pragma unroll
    for (int tn = 0; tn < 4; tn++)
    #pragma unroll
    for (int r = 0; r < 4; r++) {
        int il = tm*16 + lh*4 + r;
        int d  = tn*16 + ll;
        int sg = qb*64 + il;
        o[((size_t)(b*1024 + sg)) * 1024 + hh*64 + d] = f2b(oacc[tm][tn][r]);
    }
}
#undef SM_NEAR
#undef SM_FAR

// ---------------------------------------------------------------------------
// Finisher: rebuild per-row buckets from band+lohi, o = (o_un + br@rel_v)/sum.
// ---------------------------------------------------------------------------
__global__ __launch_bounds__(256) void attn_fin(
    const u16* __restrict__ band, const float* __restrict__ lohi,
    const void* __restrict__ rel_v, u16* __restrict__ o, const u32* __restrict__ diag)
{
    __shared__ float rv[33][64];
    const int f32 = (int)diag[1];
    int t = threadIdx.x;
    for (int i = t; i < 33*64; i += 256) (&rv[0][0])[i] = ldx(rel_v, i, f32);
    __syncthreads();
    int d = t & 63;
    #pragma unroll
    for (int rg = 0; rg < 4; rg++) {
        int row = blockIdx.x * 16 + rg * 4 + (t >> 6);   // bh*1024 + s
        int s = row & 1023;
        const u64* bd8 = (const u64*)(band + (size_t)row * 32);
        u64 bq[4] = { bd8[0], bd8[1], bd8[2], bd8[3] };
        float lo = lohi[(size_t)row * 2], hi = lohi[(size_t)row * 2 + 1];
        float denom = lo + hi;
        float w2 = lo * rv[0][d] + hi * rv[32][d];
        #pragma unroll
        for (int dd = 1; dd < 32; dd++) {
            int j = s + dd - 16;
            if (j >= 0 && j < 1024) {
                u16 raw = (u16)(bq[(dd - 1) >> 2] >> (((dd - 1) & 3) * 16));
                float bv = b2f(raw);
                denom += bv;
                w2 += bv * rv[dd][d];
            }
        }
        int bb = row >> 14, h = (row >> 10) & 15;
        size_t idx = (size_t)(bb*1024 + s) * 1024 + h*64 + d;
        o[idx] = f2b((b2f(o[idx]) + w2) / denom);
    }
}

// ---------------------------------------------------------------------------
// out = LayerNorm(xa + xb) * g + b.  Vectorized: thread owns 4 contiguous
// elements (float4 / u64 loads, u64 packed store).
// ---------------------------------------------------------------------------
__global__ __launch_bounds__(256) void ln_kernel(
    const void* __restrict__ xa, int xa_ext, const u16* __restrict__ xb,
    const void* __restrict__ g, const void* __restrict__ bb,
    void* __restrict__ out, int final_out, const u32* __restrict__ diag)
{
    __shared__ float redS[4], redS2[4];
    const int inf32 = (int)diag[1];
    const int af32 = xa_ext ? inf32 : 0;
    const int of32 = final_out ? inf32 : 0;
    int row = blockIdx.x;
    int t = threadIdx.x;
    size_t base = (size_t)row << 10;
    int c0 = t * 4;
    float v[4]; float s = 0.f, s2 = 0.f;
    if (af32) {
        float4 a = *(const float4*)((const float*)xa + base + c0);
        v[0] = a.x; v[1] = a.y; v[2] = a.z; v[3] = a.w;
    } else {
        u64 xv = *(const u64*)((const u16*)xa + base + c0);
        v[0] = b2f((u16)xv);         v[1] = b2f((u16)(xv >> 16));
        v[2] = b2f((u16)(xv >> 32)); v[3] = b2f((u16)(xv >> 48));
    }
    {
        u64 bv_ = *(const u64*)(xb + base + c0);
        v[0] += b2f((u16)bv_);         v[1] += b2f((u16)(bv_ >> 16));
        v[2] += b2f((u16)(bv_ >> 32)); v[3] += b2f((u16)(bv_ >> 48));
    }
    #pragma unroll
    for (int i = 0; i < 4; i++) { s += v[i]; s2 += v[i] * v[i]; }
    #pragma unroll
    for (int off = 1; off < 64; off <<= 1) {
        s  += __shfl_xor(s,  off, 64);
        s2 += __shfl_xor(s2, off, 64);
    }
    int w = t >> 6;
    if ((t & 63) == 0) { redS[w] = s; redS2[w] = s2; }
    __syncthreads();
    float S  = redS[0] + redS[1] + redS[2] + redS[3];
    float S2 = redS2[0] + redS2[1] + redS2[2] + redS2[3];
    float mean = S * (1.f / 1024.f);
    float var  = S2 * (1.f / 1024.f) - mean * mean;
    float rstd = rsqrtf(var + 1e-5f);
    float gg[4], bv2[4];
    if (inf32) {
        float4 a = *(const float4*)((const float*)g + c0);
        float4 c = *(const float4*)((const float*)bb + c0);
        gg[0]=a.x; gg[1]=a.y; gg[2]=a.z; gg[3]=a.w;
        bv2[0]=c.x; bv2[1]=c.y; bv2[2]=c.z; bv2[3]=c.w;
    } else {
        u64 gv = *(const u64*)((const u16*)g + c0);
        u64 cv = *(const u64*)((const u16*)bb + c0);
        gg[0]=b2f((u16)gv); gg[1]=b2f((u16)(gv>>16)); gg[2]=b2f((u16)(gv>>32)); gg[3]=b2f((u16)(gv>>48));
        bv2[0]=b2f((u16)cv); bv2[1]=b2f((u16)(cv>>16)); bv2[2]=b2f((u16)(cv>>32)); bv2[3]=b2f((u16)(cv>>48));
    }
    float r[4];
    #pragma unroll
    for (int i = 0; i < 4; i++) r[i] = (v[i] - mean) * rstd * gg[i] + bv2[i];
    if (of32) {
        float4 ov; ov.x = r[0]; ov.y = r[1]; ov.z = r[2]; ov.w = r[3];
        *(float4*)((float*)out + base + c0) = ov;
    } else {
        u64 pv = (u64)f2b(r[0]) | ((u64)f2b(r[1]) << 16)
               | ((u64)f2b(r[2]) << 32) | ((u64)f2b(r[3]) << 48);
        *(u64*)((u16*)out + base + c0) = pv;
    }
}

// ---------------------------------------------------------------------------
extern "C" void kernel_launch(void* const* d_in, const int* in_sizes, int n_in,
                              void* d_out, int out_size, void* d_ws, size_t ws_size,
                              hipStream_t stream)
{
    (void)in_sizes; (void)n_in;
    const void* x     = d_in[0];
    const int*  mask  = (const int*)d_in[1];
    const void* wq    = d_in[2];
    const void* bq    = d_in[3];
    const void* wk    = d_in[4];
    const void* bk    = d_in[5];
    const void* wv    = d_in[6];
    const void* bv    = d_in[7];
    const void* wo    = d_in[8];
    const void* bo    = d_in[9];
    const void* rel_k = d_in[10];
    const void* rel_v = d_in[11];
    const void* fc1w  = d_in[12];
    const void* fc1b  = d_in[13];
    const void* fc2w  = d_in[14];
    const void* fc2b  = d_in[15];
    const void* ln1g  = d_in[16];
    const void* ln1b  = d_in[17];
    const void* ln2g  = d_in[18];
    const void* ln2b  = d_in[19];

    const size_t NEED = 117440768;   // 112 MiB (validated in round 4/5)
    if (ws_size < NEED) {
        float mb = -(float)(double)(ws_size >> 20);
        diag_fill_f32<<<dim3(2048), 256, 0, stream>>>((float*)d_out, mb, out_size);
        return;
    }

    // ws layout (bytes). diag never aliased.
    char* ws = (char*)d_ws;
    u32*   diag  = (u32*)  (ws + 0);            // 256 B
    u16*   fc1T  = (u16*)  (ws + 256);
    u16*   fc2T  = (u16*)  (ws + 8388864);
    u16*   woT   = (u16*)  (ws + 16777472);
    u16*   wqT   = (u16*)  (ws + 18874624);
    u16*   wkT   = (u16*)  (ws + 20971776);     // contiguous after wqT
    u16*   wvT   = (u16*)  (ws + 23068928);     // contiguous after wkT
    u16*   q_    = (u16*)  (ws + 25166080);
    u16*   k_    = (u16*)  (ws + 41943296);
    u16*   vT_   = (u16*)  (ws + 58720512);
    u16*   qr_   = (u16*)  (ws + 75497728);     // 8650752
    u16*   o_    = (u16*)  (ws + 84148480);     // ..100925696
    u16*   band_ = (u16*)  (ws + 100925696);    // 8388608 -> 109314304
    float* lohi_ = (float*)(ws + 109314304);    // 1048576 -> 110362880
    u64*   mb_   = (u64*)  (ws + 110362880);    // 1048576 -> 111411456
    u16*   xbf_  = (u16*)  (ws + 84148480);     // alias o_ (dead until attn writes it)
    u16*   ao_   = (u16*)  (ws + 58720512);     // alias vT_  [dead after attn]
    u16*   x1_   = (u16*)  (ws + 16777472);     // alias woT..q head [dead then]
    u16*   ff1   = (u16*)  (ws + 33554688);     // alias q tail,k,vT,qr,o [dead]
    u16*   ao2   = (u16*)  (ws + 100663552);    // alias band/lohi/mb [dead after fin]

    init_diag<<<dim3(1), 64, 0, stream>>>((const u16*)x, diag);
    xconv<<<dim3(4096), 256, 0, stream>>>(x, xbf_, diag);
    mask_bits_kernel<<<dim3(8192), 256, 0, stream>>>(mask, mb_, diag);

    transpose4_in<<<dim3(32, 32, 4), 256, 0, stream>>>(wq, wk, wv, wo,
                                                       wqT, wkT, wvT, woT, diag);
    transpose_in<<<dim3(128, 32), 256, 0, stream>>>(fc1w, fc1T, 1024, 4096, diag);
    transpose_in<<<dim3(32, 128), 256, 0, stream>>>(fc2w, fc2T, 4096, 1024, diag);

    // fused QKV: B = [wqT|wkT|wvT] (contiguous, 3072x1024); q pre-scaled 0.125
    gemm_qkv<<<dim3(64, 24), 256, 0, stream>>>((const u16*)xbf_, wqT,
                                               bq, bk, bv, q_, k_, vT_, diag);

    qr_mfma<<<dim3(512), 256, 0, stream>>>(q_, rel_k, qr_, diag);
    attn_kernel<<<dim3(512), 256, 0, stream>>>(q_, k_, vT_, qr_, mb_, band_, lohi_, o_, diag);
    attn_fin<<<dim3(8192), 256, 0, stream>>>(band_, lohi_, rel_v, o_, diag);

    gemm_bt<3><<<dim3(64, 8), 256, 0, stream>>>(o_, woT, bo, ao_, 8192, 1024, 1024, 1.0f, diag);
    ln_kernel<<<dim3(8192), 256, 0, stream>>>(x, 1, ao_, ln1g, ln1b, x1_, 0, diag);
    gemm_bt<4><<<dim3(64, 32), 256, 0, stream>>>(x1_, fc1T, fc1b, ff1, 8192, 4096, 1024, 1.0f, diag);
    gemm_bt<3><<<dim3(64, 8), 256, 0, stream>>>(ff1, fc2T, fc2b, ao2, 8192, 1024, 4096, 1.0f, diag);
    ln_kernel<<<dim3(8192), 256, 0, stream>>>(x1_, 0, ao2, ln2g, ln2b, d_out, 1, diag);
}

// Round 11
// 707.923 us; speedup vs baseline: 1.1001x; 1.0284x over previous
//
#include <hip/hip_runtime.h>

typedef unsigned short u16;
typedef unsigned int   u32;
typedef unsigned long long u64;
using bf16x8 = __attribute__((ext_vector_type(8))) short;
using f32x4  = __attribute__((ext_vector_type(4))) float;

__device__ __forceinline__ float b2f(u16 u) {
    union { unsigned int i; float f; } x; x.i = ((unsigned int)u) << 16; return x.f;
}
__device__ __forceinline__ u16 f2b(float f) {
    union { float f; unsigned int i; } x; x.f = f;
    unsigned int i = x.i;
    return (u16)((i + 0x7FFFu + ((i >> 16) & 1u)) >> 16);  // RNE, inputs never NaN
}
// flag-aware scalar load of an INPUT tensor element (f32 or bf16 storage)
__device__ __forceinline__ float ldx(const void* p, size_t i, int f32) {
    return f32 ? ((const float*)p)[i] : b2f(((const u16*)p)[i]);
}
// async global->LDS, 16B per lane; lptr must be wave-uniform (HW: base+lane*16)
__device__ __forceinline__ void gload16(const void* g, void* l) {
    __builtin_amdgcn_global_load_lds(
        (const __attribute__((address_space(1))) void*)g,
        (__attribute__((address_space(3))) void*)l, 16, 0, 0);
}

// ---------------------------------------------------------------------------
// init_diag: diag[1] = inputs-are-f32 flag; diag[2] = mask-all-ones (refined
// by prep_kernel's mask stage).
// ---------------------------------------------------------------------------
__global__ __launch_bounds__(64) void init_diag(const u16* __restrict__ x, u32* diag)
{
    int lane = threadIdx.x;
    u16 v = x[lane * 2];
    int e = (v >> 7) & 0xFF;
    bool extreme = (e < 100) | (e > 154);
    u64 m = __ballot(extreme);
    if (lane == 0) { diag[0] = 0u; diag[1] = (m != 0ull) ? 1u : 0u; diag[2] = 1u; }
}

__global__ __launch_bounds__(256) void diag_fill_f32(float* __restrict__ out, float val, int n)
{
    for (int i = blockIdx.x * 256 + threadIdx.x; i < n; i += gridDim.x * 256) out[i] = val;
}

// ---------------------------------------------------------------------------
// shared transpose body (f32/bf16 in -> bf16 out^T), 32x32 tile per block.
// ---------------------------------------------------------------------------
__device__ __forceinline__ void do_transpose(
    const void* in, u16* out, int R, int C, int bx, int by, int f32,
    u16 (*tile)[33], int t)
{
    int tx = t & 31, ty = t >> 5;
    #pragma unroll
    for (int i = ty; i < 32; i += 8)
        tile[i][tx] = f2b(ldx(in, (size_t)(by + i) * C + bx + tx, f32));
    __syncthreads();
    #pragma unroll
    for (int i = ty; i < 32; i += 8) out[(size_t)(bx + i) * R + by + tx] = tile[tx][i];
}

// ---------------------------------------------------------------------------
// R11: merged preprocessing — one launch replaces {xconv, mask_bits,
// transpose4, transpose fc1, transpose fc2} (5 dispatches -> 1; independent
// blocks overlap). Block ranges:
//   [0,4096)       xconv: x -> xbf (bf16)
//   [4096,12288)   mask -> bitmask (int4 loads, shfl-OR pack)
//   [12288,16384)  4x 1024^2 weight transpose (wq,wk,wv,wo)
//   [16384,20480)  fc1 transpose (1024x4096 -> 4096x1024)
//   [20480,24576)  fc2 transpose (4096x1024 -> 1024x4096)
// ---------------------------------------------------------------------------
__global__ __launch_bounds__(256) void prep_kernel(
    const void* __restrict__ x, u16* __restrict__ xb,
    const int* __restrict__ mask, u64* __restrict__ mb,
    const void* __restrict__ wq, const void* __restrict__ wk,
    const void* __restrict__ wv, const void* __restrict__ wo,
    u16* __restrict__ wqT, u16* __restrict__ wkT,
    u16* __restrict__ wvT, u16* __restrict__ woT,
    const void* __restrict__ fc1w, u16* __restrict__ fc1T,
    const void* __restrict__ fc2w, u16* __restrict__ fc2T,
    u32* __restrict__ diag)
{
    __shared__ u16 tile[32][33];
    const int bid = blockIdx.x;
    const int t = threadIdx.x;
    const int f32 = (int)diag[1];

    if (bid < 4096) {                                    // ---- xconv
        size_t i0 = ((size_t)bid * 256 + t) * 8;
        if (f32) {
            const float4* p = (const float4*)((const float*)x + i0);
            float4 a = p[0], b = p[1];
            bf16x8 v;
            v[0]=(short)f2b(a.x); v[1]=(short)f2b(a.y); v[2]=(short)f2b(a.z); v[3]=(short)f2b(a.w);
            v[4]=(short)f2b(b.x); v[5]=(short)f2b(b.y); v[6]=(short)f2b(b.z); v[7]=(short)f2b(b.w);
            *(bf16x8*)(xb + i0) = v;
        } else {
            *(bf16x8*)(xb + i0) = *(const bf16x8*)((const u16*)x + i0);
        }
    } else if (bid < 12288) {                            // ---- mask bits
        int mblk = bid - 4096;
        int lane = t & 63, wv_ = t >> 6;
        int gw0 = mblk * 16 + wv_ * 4 + (lane >> 4);
        const int4* p = (const int4*)(mask + (size_t)gw0 * 64 + (lane & 15) * 4);
        int4 m = *p;
        u64 v = ((u64)(m.x != 0)        | ((u64)(m.y != 0) << 1)
               | ((u64)(m.z != 0) << 2) | ((u64)(m.w != 0) << 3)) << ((lane & 15) * 4);
        v |= __shfl_xor(v, 1, 64);
        v |= __shfl_xor(v, 2, 64);
        v |= __shfl_xor(v, 4, 64);
        v |= __shfl_xor(v, 8, 64);
        if ((lane & 15) == 0) {
            mb[gw0] = v;
            if (v != ~0ull) atomicAnd(&diag[2], 0u);
        }
    } else if (bid < 16384) {                            // ---- 4x 1024^2 T
        int l = bid - 12288;
        int z = l >> 10, rem = l & 1023;
        const void* in; u16* out;
        switch (z) {
            case 0:  in = wq; out = wqT; break;
            case 1:  in = wk; out = wkT; break;
            case 2:  in = wv; out = wvT; break;
            default: in = wo; out = woT; break;
        }
        do_transpose(in, out, 1024, 1024, (rem & 31) << 5, (rem >> 5) << 5, f32, tile, t);
    } else if (bid < 20480) {                            // ---- fc1 T
        int l = bid - 16384;
        do_transpose(fc1w, fc1T, 1024, 4096, (l & 127) << 5, (l >> 7) << 5, f32, tile, t);
    } else {                                             // ---- fc2 T
        int l = bid - 20480;
        do_transpose(fc2w, fc2T, 4096, 1024, (l & 31) << 5, (l >> 5) << 5, f32, tile, t);
    }
}

// ---------------------------------------------------------------------------
// MFMA bf16 GEMM, C = (A(MxK) @ Bt(NxK)^T + bias) * scale. A always bf16.
// 128x128 tile, BK=32, 256 threads (4 waves x 64x64). 2-phase double-buffer
// (R5 config, inside the 728 us measurement). Default block order (R9's
// XCD remap regressed: A-traffic dominates and round-robin spreads A).
// Swizzle: pre-swizzled global source + swizzled fragment read (involution).
// MODE 1: bf16 -> (B,H,S,64); 2: bf16 -> (B,H,64,S); 3: bf16 row-major;
// MODE 4: bf16 relu row-major.
// ---------------------------------------------------------------------------
template<int MODE>
__global__ __launch_bounds__(256) void gemm_bt(
    const void* __restrict__ Av, const u16* __restrict__ Bt,
    const void* __restrict__ bias, u16* __restrict__ outp,
    int M, int N, int K, float scale, const u32* __restrict__ diag)
{
    __shared__ alignas(16) u16 lds_a[2][4096];
    __shared__ alignas(16) u16 lds_b[2][4096];
    const int bf32 = (int)diag[1];
    const int t = threadIdx.x;
    const int w = t >> 6, lane = t & 63;
    const int wm = (w >> 1) << 6, wn = (w & 1) << 6;
    const int ll = lane & 15, lh = lane >> 4;

    const size_t rowA = (size_t)blockIdx.x * 128;
    const size_t rowB = (size_t)blockIdx.y * 128;
    const u16* aBase = (const u16*)Av + rowA * K;
    const u16* bBase = Bt + rowB * K;

    const int sr = w * 32 + (lane >> 2);                 // chunk-0 row
    const int sj = (lane & 3) ^ ((lane >> 3) & 3);       // (sr>>1)&3 == (lane>>3)&3
    const size_t gOff0 = (size_t)sr * K + sj * 8;
    const size_t gOff1 = (size_t)(sr + 16) * K + sj * 8;

    const int rdcol = (lh ^ ((ll >> 1) & 3)) * 8;

    f32x4 acc[4][4] = {};

#define STAGE(BUF, K0) do {                                                    \
        gload16(aBase + gOff0 + (K0), &lds_a[BUF][(w * 32) * 32]);             \
        gload16(aBase + gOff1 + (K0), &lds_a[BUF][(w * 32 + 16) * 32]);        \
        gload16(bBase + gOff0 + (K0), &lds_b[BUF][(w * 32) * 32]);             \
        gload16(bBase + gOff1 + (K0), &lds_b[BUF][(w * 32 + 16) * 32]);        \
    } while (0)

#define GCOMPUTE(BUF) do {                                                     \
        bf16x8 af[4], bfg[4];                                                  \
        _Pragma("unroll")                                                      \
        for (int tm = 0; tm < 4; tm++)                                         \
            af[tm]  = *(const bf16x8*)&lds_a[BUF][(wm + tm * 16 + ll) * 32 + rdcol]; \
        _Pragma("unroll")                                                      \
        for (int tn = 0; tn < 4; tn++)                                         \
            bfg[tn] = *(const bf16x8*)&lds_b[BUF][(wn + tn * 16 + ll) * 32 + rdcol]; \
        _Pragma("unroll")                                                      \
        for (int tm = 0; tm < 4; tm++)                                         \
            _Pragma("unroll")                                                  \
            for (int tn = 0; tn < 4; tn++)                                     \
                acc[tm][tn] = __builtin_amdgcn_mfma_f32_16x16x32_bf16(         \
                    af[tm], bfg[tn], acc[tm][tn], 0, 0, 0);                    \
    } while (0)

    STAGE(0, 0);
    __syncthreads();
    for (int k0 = 0; k0 < K; k0 += 64) {
        if (k0 + 32 < K) STAGE(1, k0 + 32);   // issue next tile BEFORE compute
        GCOMPUTE(0);
        __syncthreads();                       // drains vmcnt (next tile ready)
        if (k0 + 64 < K) STAGE(0, k0 + 64);
        GCOMPUTE(1);
        __syncthreads();
    }
#undef STAGE
#undef GCOMPUTE

    #pragma unroll
    for (int tm = 0; tm < 4; tm++)
    #pragma unroll
    for (int tn = 0; tn < 4; tn++)
    #pragma unroll
    for (int r = 0; r < 4; r++) {
        int gr = (int)rowA + wm + tm*16 + lh*4 + r;      // C row (M)
        int gc = (int)rowB + wn + tn*16 + ll;            // C col (N)
        float v = (acc[tm][tn][r] + ldx(bias, gc, bf32)) * scale;
        if (MODE == 1) {
            int b = gr >> 10, s = gr & 1023, h = gc >> 6, d = gc & 63;
            outp[((((size_t)(b*16 + h) << 10) | s) << 6) + d] = f2b(v);
        } else if (MODE == 2) {
            int b = gr >> 10, s = gr & 1023, h = gc >> 6, d = gc & 63;
            outp[((((size_t)(b*16 + h) << 6) | d) << 10) + s] = f2b(v);
        } else if (MODE == 3) {
            outp[(size_t)gr * N + gc] = f2b(v);
        } else {
            outp[(size_t)gr * N + gc] = f2b(fmaxf(v, 0.f));
        }
    }
}

// ---------------------------------------------------------------------------
// Fused QKV GEMM: B = [wqT|wkT|wvT] contiguous (3072x1024). which = by>>3
// selects bias/scale/layout: q,k -> (B,H,S,64) [q scaled 0.125];
// v -> (B,H,64,S). Grid dim3(64, 24).
// ---------------------------------------------------------------------------
__global__ __launch_bounds__(256) void gemm_qkv(
    const u16* __restrict__ Av, const u16* __restrict__ Bt,
    const void* __restrict__ bq, const void* __restrict__ bk,
    const void* __restrict__ bv,
    u16* __restrict__ qo, u16* __restrict__ ko, u16* __restrict__ vo,
    const u32* __restrict__ diag)
{
    const int K = 1024;
    __shared__ alignas(16) u16 lds_a[2][4096];
    __shared__ alignas(16) u16 lds_b[2][4096];
    const int bf32 = (int)diag[1];
    const int t = threadIdx.x;
    const int w = t >> 6, lane = t & 63;
    const int wm = (w >> 1) << 6, wn = (w & 1) << 6;
    const int ll = lane & 15, lh = lane >> 4;

    const size_t rowA = (size_t)blockIdx.x * 128;
    const size_t rowB = (size_t)blockIdx.y * 128;
    const u16* aBase = (const u16*)Av + rowA * K;
    const u16* bBase = Bt + rowB * K;

    const int which = (int)(blockIdx.y >> 3);            // 0=q,1=k,2=v
    const float scale = (which == 0) ? 0.125f : 1.0f;
    const void* bias = (which == 0) ? bq : ((which == 1) ? bk : bv);
    u16* outqk = (which == 0) ? qo : ko;

    const int sr = w * 32 + (lane >> 2);
    const int sj = (lane & 3) ^ ((lane >> 3) & 3);
    const size_t gOff0 = (size_t)sr * K + sj * 8;
    const size_t gOff1 = (size_t)(sr + 16) * K + sj * 8;

    const int rdcol = (lh ^ ((ll >> 1) & 3)) * 8;

    f32x4 acc[4][4] = {};

#define STAGE(BUF, K0) do {                                                    \
        gload16(aBase + gOff0 + (K0), &lds_a[BUF][(w * 32) * 32]);             \
        gload16(aBase + gOff1 + (K0), &lds_a[BUF][(w * 32 + 16) * 32]);        \
        gload16(bBase + gOff0 + (K0), &lds_b[BUF][(w * 32) * 32]);             \
        gload16(bBase + gOff1 + (K0), &lds_b[BUF][(w * 32 + 16) * 32]);        \
    } while (0)

#define GCOMPUTE(BUF) do {                                                     \
        bf16x8 af[4], bfg[4];                                                  \
        _Pragma("unroll")                                                      \
        for (int tm = 0; tm < 4; tm++)                                         \
            af[tm]  = *(const bf16x8*)&lds_a[BUF][(wm + tm * 16 + ll) * 32 + rdcol]; \
        _Pragma("unroll")                                                      \
        for (int tn = 0; tn < 4; tn++)                                         \
            bfg[tn] = *(const bf16x8*)&lds_b[BUF][(wn + tn * 16 + ll) * 32 + rdcol]; \
        _Pragma("unroll")                                                      \
        for (int tm = 0; tm < 4; tm++)                                         \
            _Pragma("unroll")                                                  \
            for (int tn = 0; tn < 4; tn++)                                     \
                acc[tm][tn] = __builtin_amdgcn_mfma_f32_16x16x32_bf16(         \
                    af[tm], bfg[tn], acc[tm][tn], 0, 0, 0);                    \
    } while (0)

    STAGE(0, 0);
    __syncthreads();
    for (int k0 = 0; k0 < K; k0 += 64) {
        if (k0 + 32 < K) STAGE(1, k0 + 32);
        GCOMPUTE(0);
        __syncthreads();
        if (k0 + 64 < K) STAGE(0, k0 + 64);
        GCOMPUTE(1);
        __syncthreads();
    }
#undef STAGE
#undef GCOMPUTE

    #pragma unroll
    for (int tm = 0; tm < 4; tm++)
    #pragma unroll
    for (int tn = 0; tn < 4; tn++)
    #pragma unroll
    for (int r = 0; r < 4; r++) {
        int gr = (int)rowA + wm + tm*16 + lh*4 + r;      // row in [0,8192)
        int gc = (int)rowB + wn + tn*16 + ll;            // col in [0,3072)
        int gcl = gc & 1023;
        float v = (acc[tm][tn][r] + ldx(bias, gcl, bf32)) * scale;
        int b = gr >> 10, s = gr & 1023, h = gcl >> 6, d = gcl & 63;
        if (which != 2)
            outqk[((((size_t)(b*16 + h) << 10) | s) << 6) + d] = f2b(v);
        else
            vo[((((size_t)(b*16 + h) << 6) | d) << 10) + s] = f2b(v);
    }
}

// ---------------------------------------------------------------------------
// qr via MFMA: qr[row][rr] = q_scaled[row][:] . rel_k[rr][:]  (M=131072,
// N=33, K=64 GEMM). rel_k staged once as bf16 in LDS, rows 33..47 zeroed.
// ---------------------------------------------------------------------------
__global__ __launch_bounds__(256) void qr_mfma(
    const u16* __restrict__ q, const void* __restrict__ rel_k,
    u16* __restrict__ qr, const u32* __restrict__ diag)
{
    const int f32 = (int)diag[1];
    __shared__ alignas(16) u16 rk_lds[48 * 64];      // 6144 B
    int t = threadIdx.x;
    for (int i = t; i < 48 * 64; i += 256)
        rk_lds[i] = (i < 33 * 64) ? f2b(ldx(rel_k, i, f32)) : (u16)0;
    __syncthreads();

    const int lane = t & 63, w = t >> 6;
    const int ll = lane & 15, lh = lane >> 4;
    const size_t rowbase = (size_t)blockIdx.x * 256 + w * 64;

    f32x4 acc[4][3] = {};
    #pragma unroll
    for (int kk = 0; kk < 2; kk++) {
        bf16x8 bf[3];
        #pragma unroll
        for (int rt = 0; rt < 3; rt++)
            bf[rt] = *(const bf16x8*)&rk_lds[(rt * 16 + ll) * 64 + kk * 32 + lh * 8];
        #pragma unroll
        for (int tm = 0; tm < 4; tm++) {
            bf16x8 af = *(const bf16x8*)(q + (rowbase + tm * 16 + ll) * 64 + kk * 32 + lh * 8);
            #pragma unroll
            for (int rt = 0; rt < 3; rt++)
                acc[tm][rt] = __builtin_amdgcn_mfma_f32_16x16x32_bf16(
                    af, bf[rt], acc[tm][rt], 0, 0, 0);
        }
    }

    #pragma unroll
    for (int tm = 0; tm < 4; tm++)
    #pragma unroll
    for (int rt = 0; rt < 3; rt++) {
        int rr = rt * 16 + ll;
        if (rr < 33) {
            #pragma unroll
            for (int r = 0; r < 4; r++) {
                size_t row = rowbase + tm * 16 + lh * 4 + r;
                qr[row * 33 + rr] = f2b(acc[tm][rt][r]);
            }
        }
    }
}

// ---------------------------------------------------------------------------
// Fused relative attention — R5 structure (161 us measured; best).
// Raw lgkm-only barriers + named reg prefetch, qr in LDS, deferred lo/hi
// reduction, mask-free duplicated bodies, setprio, XCD remap.
// ---------------------------------------------------------------------------
#define SM_NEAR(MASKED)                                                        \
        _Pragma("unroll")                                                      \
        for (int tm = 0; tm < 4; tm++)                                         \
        _Pragma("unroll")                                                      \
        for (int r = 0; r < 4; r++) {                                          \
            int il = tm*16 + lh*4 + r;                                         \
            u64 bits = MASKED ? mrow[(size_t)il * 16 + kb] : ~0ull;            \
            int ig = qb*64 + il;                                               \
            float lo_p = 0.f, hi_p = 0.f;                                      \
            _Pragma("unroll")                                                  \
            for (int tn = 0; tn < 4; tn++) {                                   \
                int jl = tn*16 + ll;                                           \
                int d0 = kb*64 + jl - ig;                                      \
                int dd = (d0 < -16 ? -16 : (d0 > 16 ? 16 : d0)) + 16;          \
                float sc = sacc[tm][tn][r] + b2f(qr_lds[w][il][dd]);           \
                float pf = __expf(fminf(sc, 30.f));                            \
                if (MASKED) pf = ((bits >> jl) & 1ull) ? pf : 0.f;             \
                p_lds[w][il][jl] = f2b(pf);                                    \
                if (dd == 0) lo_p += pf;                                       \
                else if (dd == 32) hi_p += pf;                                 \
                else bandb[(size_t)il * 32 + dd - 1] = f2b(pf);                \
            }                                                                  \
            slo[tm*4 + r] += lo_p; shi[tm*4 + r] += hi_p;                      \
        }

#define SM_FAR(MASKED)                                                         \
        _Pragma("unroll")                                                      \
        for (int tm = 0; tm < 4; tm++)                                         \
        _Pragma("unroll")                                                      \
        for (int r = 0; r < 4; r++) {                                          \
            int il = tm*16 + lh*4 + r;                                         \
            u64 bits = MASKED ? mrow[(size_t)il * 16 + kb] : ~0ull;            \
            float qrv = b2f(qr_lds[w][il][sel]);                               \
            float part = 0.f;                                                  \
            _Pragma("unroll")                                                  \
            for (int tn = 0; tn < 4; tn++) {                                   \
                int jl = tn*16 + ll;                                           \
                float sc = sacc[tm][tn][r] + qrv;                              \
                float pf = __expf(fminf(sc, 30.f));                            \
                if (MASKED) pf = ((bits >> jl) & 1ull) ? pf : 0.f;             \
                p_lds[w][il][jl] = f2b(pf);                                    \
                part += pf;                                                    \
            }                                                                  \
            if (sel == 0) slo[tm*4 + r] += part; else shi[tm*4 + r] += part;   \
        }

__global__ __launch_bounds__(256) void attn_kernel(
    const u16* __restrict__ q, const u16* __restrict__ k, const u16* __restrict__ vT,
    const u16* __restrict__ qr, const u64* __restrict__ mbits,
    u16* __restrict__ band, float* __restrict__ lohi,
    u16* __restrict__ o, const u32* __restrict__ diag)
{
    __shared__ alignas(16) u16 k_lds[4096];
    __shared__ alignas(16) u16 v_lds[4096];
    __shared__ alignas(16) u16 p_lds[4][64][72];
    __shared__ alignas(16) u16 qr_lds[4][64][33];

    const int g  = blockIdx.x;
    const int vb = (g & 7) * 64 + (g >> 3);          // bijective on [0,512)
    const int bh = vb >> 2;
    const int w  = threadIdx.x >> 6;
    const int qb = ((vb & 3) << 2) + w;
    const int b = bh >> 4, hh = bh & 15;
    const int lane = threadIdx.x & 63;
    const int ll = lane & 15, lh = lane >> 4;
    const int t = threadIdx.x;
    const int allm = (int)diag[2];

    bf16x8 aq[4][2];
    const u16* qbase = q + ((size_t)bh * 1024 + qb * 64) * 64;
    #pragma unroll
    for (int tm = 0; tm < 4; tm++)
        #pragma unroll
        for (int kk = 0; kk < 2; kk++)
            aq[tm][kk] = *(const bf16x8*)(qbase + (size_t)(tm*16 + ll) * 64 + kk*32 + lh*8);

    const u16* qrb = qr + ((size_t)bh * 1024 + qb * 64) * 33;
    {
        const u32* srcq = (const u32*)qrb;
        u32* dstq = (u32*)&qr_lds[w][0][0];
        #pragma unroll
        for (int i = 0; i < 17; i++) {
            int idx = lane + (i << 6);
            if (idx < 1056) dstq[idx] = srcq[idx];
        }
    }

    f32x4 oacc[4][4] = {};
    float slo[16], shi[16];
    #pragma unroll
    for (int i = 0; i < 16; i++) { slo[i] = 0.f; shi[i] = 0.f; }

    const u16* kbase = k + (size_t)bh * 65536;
    const u16* vbase = vT + (size_t)bh * 65536;
    const u64* mrow = mbits + ((size_t)b * 1024 + qb * 64) * 16;
    u16* bandb = band + ((size_t)bh * 1024 + qb * 64) * 32;

    const int c0 = t, c1 = t + 256;
    const u16 *kp0, *kp1, *vp0, *vp1;
    {
        int tn = c0 >> 7, kk2 = (c0 >> 6) & 1, qd = (c0 >> 4) & 3, l2 = c0 & 15;
        kp0 = kbase + (size_t)(tn*16 + l2)*64 + kk2*32 + qd*8;
        vp0 = vbase + (size_t)(tn*16 + l2)*1024 + kk2*32 + qd*8;
    }
    {
        int tn = c1 >> 7, kk2 = (c1 >> 6) & 1, qd = (c1 >> 4) & 3, l2 = c1 & 15;
        kp1 = kbase + (size_t)(tn*16 + l2)*64 + kk2*32 + qd*8;
        vp1 = vbase + (size_t)(tn*16 + l2)*1024 + kk2*32 + qd*8;
    }
    bf16x8 pk0 = *(const bf16x8*)kp0;                // tile 0
    bf16x8 pk1 = *(const bf16x8*)kp1;
    bf16x8 pv0 = *(const bf16x8*)vp0;
    bf16x8 pv1 = *(const bf16x8*)vp1;

    for (int kb = 0; kb < 16; kb++) {
        asm volatile("s_waitcnt lgkmcnt(0)" ::: "memory");
        __builtin_amdgcn_s_barrier();
        *(bf16x8*)&k_lds[c0*8] = pk0;          // commit (compiler waits vmcnt)
        *(bf16x8*)&k_lds[c1*8] = pk1;
        *(bf16x8*)&v_lds[c0*8] = pv0;
        *(bf16x8*)&v_lds[c1*8] = pv1;
        if (kb < 15) {                         // issue t+1 loads; stay in flight
            pk0 = *(const bf16x8*)(kp0 + (size_t)(kb + 1) * 4096);
            pk1 = *(const bf16x8*)(kp1 + (size_t)(kb + 1) * 4096);
            pv0 = *(const bf16x8*)(vp0 + (size_t)(kb + 1) * 64);
            pv1 = *(const bf16x8*)(vp1 + (size_t)(kb + 1) * 64);
        }
        asm volatile("s_waitcnt lgkmcnt(0)" ::: "memory");
        __builtin_amdgcn_s_barrier();

        f32x4 sacc[4][4] = {};
        #pragma unroll
        for (int kk = 0; kk < 2; kk++) {
            bf16x8 bk[4];
            #pragma unroll
            for (int tn = 0; tn < 4; tn++)
                bk[tn] = *(const bf16x8*)&k_lds[(((tn*2 + kk) << 6) + lane) * 8];
            __builtin_amdgcn_s_setprio(1);
            #pragma unroll
            for (int tm = 0; tm < 4; tm++)
                #pragma unroll
                for (int tn = 0; tn < 4; tn++)
                    sacc[tm][tn] = __builtin_amdgcn_mfma_f32_16x16x32_bf16(
                        aq[tm][kk], bk[tn], sacc[tm][tn], 0, 0, 0);
            __builtin_amdgcn_s_setprio(0);
        }

        const int diff = kb - qb;
        const int sel = (diff < 0) ? 0 : 32;   // in scope for all expansions
        if (diff >= -1 && diff <= 1) {
            if (allm) { SM_NEAR(0) } else { SM_NEAR(1) }
        } else {
            if (allm) { SM_FAR(0) } else { SM_FAR(1) }
        }

        #pragma unroll
        for (int kk = 0; kk < 2; kk++) {
            bf16x8 ap[4], bv[4];
            #pragma unroll
            for (int tm = 0; tm < 4; tm++)
                ap[tm] = *(const bf16x8*)&p_lds[w][tm*16 + ll][kk*32 + lh*8];
            #pragma unroll
            for (int tn = 0; tn < 4; tn++)
                bv[tn] = *(const bf16x8*)&v_lds[(((tn*2 + kk) << 6) + lane) * 8];
            __builtin_amdgcn_s_setprio(1);
            #pragma unroll
            for (int tm = 0; tm < 4; tm++)
                #pragma unroll
                for (int tn = 0; tn < 4; tn++)
                    oacc[tm][tn] = __builtin_amdgcn_mfma_f32_16x16x32_bf16(
                        ap[tm], bv[tn], oacc[tm][tn], 0, 0, 0);
            __builtin_amdgcn_s_setprio(0);
        }
    }

    // deferred cross-lane (ll) reduction of lo/hi sums — once, not per tile
    #pragma unroll
    for (int i = 0; i < 16; i++) {
        float a = slo[i], c = shi[i];
        a += __shfl_xor(a, 1, 64); c += __shfl_xor(c, 1, 64);
        a += __shfl_xor(a, 2, 64); c += __shfl_xor(c, 2, 64);
        a += __shfl_xor(a, 4, 64); c += __shfl_xor(c, 4, 64);
        a += __shfl_xor(a, 8, 64); c += __shfl_xor(c, 8, 64);
        slo[i] = a; shi[i] = c;
    }

    if (ll == 0) {
        size_t row0 = (size_t)bh * 1024 + qb * 64;
        #pragma unroll
        for (int i = 0; i < 16; i++) {
            int il = (i >> 2)*16 + lh*4 + (i & 3);
            lohi[(row0 + il)*2]     = slo[i];
            lohi[(row0 + il)*2 + 1] = shi[i];
        }
    }

    #pragma unroll
    for (int tm = 0; tm < 4; tm++)
    #pragma unroll
    for (int tn = 0; tn < 4; tn++)
    #pragma unroll
    for (int r = 0; r < 4; r++) {
        int il = tm*16 + lh*4 + r;
        int d  = tn*16 + ll;
        int sg = qb*64 + il;
        o[((size_t)(b*1024 + sg)) * 1024 + hh*64 + d] = f2b(oacc[tm][tn][r]);
    }
}
#undef SM_NEAR
#undef SM_FAR

// ---------------------------------------------------------------------------
// R11: finisher via MFMA. w2[row][d] = avec[row][:] . rvT[d][:] where
// avec = [lo, band(range-masked), hi, 0-pad] (33 -> 64), rvT = rel_v^T bf16.
// Replaces the serial 31-iter scalar FMA chain per (row,d). Per block:
// 256 rows; build avec rows in LDS (stride 72 u16 = 144B: 16B-aligned,
// bank-rotating — same pattern as attn's p_lds), denom in f32 alongside;
// 2 K-chunks x 4x4 MFMA per wave; epilogue o = (o + w2)/denom (coalesced:
// d contiguous in o). Precision: rv/lo/hi get one bf16 rounding inside w2
// only (~0.5% rel of a term ~o-magnitude).
// ---------------------------------------------------------------------------
__global__ __launch_bounds__(256) void fin_mfma(
    const u16* __restrict__ band, const float* __restrict__ lohi,
    const void* __restrict__ rel_v, u16* __restrict__ o,
    const u32* __restrict__ diag)
{
    __shared__ alignas(16) u16 rvT[64 * 72];         // rvT[d][dd], dd>=33 zero
    __shared__ alignas(16) u16 a_lds[256 * 72];
    __shared__ float den_lds[256];
    const int f32 = (int)diag[1];
    const int t = threadIdx.x;

    for (int i = t; i < 64 * 64; i += 256) {
        int d = i >> 6, dd = i & 63;
        rvT[d * 72 + dd] = (dd < 33) ? f2b(ldx(rel_v, (size_t)dd * 64 + d, f32)) : (u16)0;
    }

    // build this thread's row
    const size_t row = (size_t)blockIdx.x * 256 + t;
    const int s = (int)(row & 1023);
    const u64* bd8 = (const u64*)(band + row * 32);
    u64 bq0 = bd8[0], bq1 = bd8[1], bq2 = bd8[2], bq3 = bd8[3];
    float lo = lohi[row * 2], hi = lohi[row * 2 + 1];
    float denom = lo + hi;
    u16* arow = &a_lds[t * 72];
    arow[0]  = f2b(lo);
    arow[32] = f2b(hi);
    #pragma unroll
    for (int dd = 1; dd < 32; dd++) {
        int q4 = (dd - 1) >> 2;
        u64 src = (q4 == 0) ? bq0 : (q4 == 1) ? bq1 : (q4 == 2) ? bq2 : bq3;
        u16 raw = (u16)(src >> (((dd - 1) & 3) * 16));
        int j = s + dd - 16;
        float bv = (j >= 0 && j < 1024) ? b2f(raw) : 0.f;
        denom += bv;
        arow[dd] = f2b(bv);                      // bf16 roundtrip exact
    }
    #pragma unroll
    for (int dd = 33; dd < 64; dd++) arow[dd] = 0;
    den_lds[t] = denom;
    __syncthreads();

    const int lane = t & 63, w = t >> 6;
    const int ll = lane & 15, lh = lane >> 4;
    f32x4 acc[4][4] = {};
    #pragma unroll
    for (int kk = 0; kk < 2; kk++) {
        bf16x8 bf[4];
        #pragma unroll
        for (int rt = 0; rt < 4; rt++)
            bf[rt] = *(const bf16x8*)&rvT[(rt * 16 + ll) * 72 + kk * 32 + lh * 8];
        #pragma unroll
        for (int tm = 0; tm < 4; tm++) {
            bf16x8 af = *(const bf16x8*)&a_lds[(w * 64 + tm * 16 + ll) * 72 + kk * 32 + lh * 8];
            #pragma unroll
            for (int rt = 0; rt < 4; rt++)
                acc[tm][rt] = __builtin_amdgcn_mfma_f32_16x16x32_bf16(
                    af, bf[rt], acc[tm][rt], 0, 0, 0);
        }
    }

    #pragma unroll
    for (int tm = 0; tm < 4; tm++)
    #pragma unroll
    for (int rt = 0; rt < 4; rt++)
    #pragma unroll
    for (int r = 0; r < 4; r++) {
        int lrow = w * 64 + tm * 16 + lh * 4 + r;
        size_t rr = (size_t)blockIdx.x * 256 + lrow;
        int ss = (int)(rr & 1023);
        int bb = (int)(rr >> 14), h = (int)((rr >> 10) & 15);
        size_t idx = (size_t)(bb * 1024 + ss) * 1024 + h * 64 + rt * 16 + ll;
        float dn = den_lds[lrow];
        o[idx] = f2b((b2f(o[idx]) + acc[tm][rt][r]) / dn);
    }
}

// ---------------------------------------------------------------------------
// out = LayerNorm(xa + xb) * g + b.  Vectorized: thread owns 4 contiguous
// elements (float4 / u64 loads, u64 packed store).
// ---------------------------------------------------------------------------
__global__ __launch_bounds__(256) void ln_kernel(
    const void* __restrict__ xa, int xa_ext, const u16* __restrict__ xb,
    const void* __restrict__ g, const void* __restrict__ bb,
    void* __restrict__ out, int final_out, const u32* __restrict__ diag)
{
    __shared__ float redS[4], redS2[4];
    const int inf32 = (int)diag[1];
    const int af32 = xa_ext ? inf32 : 0;
    const int of32 = final_out ? inf32 : 0;
    int row = blockIdx.x;
    int t = threadIdx.x;
    size_t base = (size_t)row << 10;
    int c0 = t * 4;
    float v[4]; float s = 0.f, s2 = 0.f;
    if (af32) {
        float4 a = *(const float4*)((const float*)xa + base + c0);
        v[0] = a.x; v[1] = a.y; v[2] = a.z; v[3] = a.w;
    } else {
        u64 xv = *(const u64*)((const u16*)xa + base + c0);
        v[0] = b2f((u16)xv);         v[1] = b2f((u16)(xv >> 16));
        v[2] = b2f((u16)(xv >> 32)); v[3] = b2f((u16)(xv >> 48));
    }
    {
        u64 bv_ = *(const u64*)(xb + base + c0);
        v[0] += b2f((u16)bv_);         v[1] += b2f((u16)(bv_ >> 16));
        v[2] += b2f((u16)(bv_ >> 32)); v[3] += b2f((u16)(bv_ >> 48));
    }
    #pragma unroll
    for (int i = 0; i < 4; i++) { s += v[i]; s2 += v[i] * v[i]; }
    #pragma unroll
    for (int off = 1; off < 64; off <<= 1) {
        s  += __shfl_xor(s,  off, 64);
        s2 += __shfl_xor(s2, off, 64);
    }
    int w = t >> 6;
    if ((t & 63) == 0) { redS[w] = s; redS2[w] = s2; }
    __syncthreads();
    float S  = redS[0] + redS[1] + redS[2] + redS[3];
    float S2 = redS2[0] + redS2[1] + redS2[2] + redS2[3];
    float mean = S * (1.f / 1024.f);
    float var  = S2 * (1.f / 1024.f) - mean * mean;
    float rstd = rsqrtf(var + 1e-5f);
    float gg[4], bv2[4];
    if (inf32) {
        float4 a = *(const float4*)((const float*)g + c0);
        float4 c = *(const float4*)((const float*)bb + c0);
        gg[0]=a.x; gg[1]=a.y; gg[2]=a.z; gg[3]=a.w;
        bv2[0]=c.x; bv2[1]=c.y; bv2[2]=c.z; bv2[3]=c.w;
    } else {
        u64 gv = *(const u64*)((const u16*)g + c0);
        u64 cv = *(const u64*)((const u16*)bb + c0);
        gg[0]=b2f((u16)gv); gg[1]=b2f((u16)(gv>>16)); gg[2]=b2f((u16)(gv>>32)); gg[3]=b2f((u16)(gv>>48));
        bv2[0]=b2f((u16)cv); bv2[1]=b2f((u16)(cv>>16)); bv2[2]=b2f((u16)(cv>>32)); bv2[3]=b2f((u16)(cv>>48));
    }
    float r[4];
    #pragma unroll
    for (int i = 0; i < 4; i++) r[i] = (v[i] - mean) * rstd * gg[i] + bv2[i];
    if (of32) {
        float4 ov; ov.x = r[0]; ov.y = r[1]; ov.z = r[2]; ov.w = r[3];
        *(float4*)((float*)out + base + c0) = ov;
    } else {
        u64 pv = (u64)f2b(r[0]) | ((u64)f2b(r[1]) << 16)
               | ((u64)f2b(r[2]) << 32) | ((u64)f2b(r[3]) << 48);
        *(u64*)((u16*)out + base + c0) = pv;
    }
}

// ---------------------------------------------------------------------------
extern "C" void kernel_launch(void* const* d_in, const int* in_sizes, int n_in,
                              void* d_out, int out_size, void* d_ws, size_t ws_size,
                              hipStream_t stream)
{
    (void)in_sizes; (void)n_in;
    const void* x     = d_in[0];
    const int*  mask  = (const int*)d_in[1];
    const void* wq    = d_in[2];
    const void* bq    = d_in[3];
    const void* wk    = d_in[4];
    const void* bk    = d_in[5];
    const void* wv    = d_in[6];
    const void* bv    = d_in[7];
    const void* wo    = d_in[8];
    const void* bo    = d_in[9];
    const void* rel_k = d_in[10];
    const void* rel_v = d_in[11];
    const void* fc1w  = d_in[12];
    const void* fc1b  = d_in[13];
    const void* fc2w  = d_in[14];
    const void* fc2b  = d_in[15];
    const void* ln1g  = d_in[16];
    const void* ln1b  = d_in[17];
    const void* ln2g  = d_in[18];
    const void* ln2b  = d_in[19];

    const size_t NEED = 117440768;   // 112 MiB (validated in round 4/5)
    if (ws_size < NEED) {
        float mb = -(float)(double)(ws_size >> 20);
        diag_fill_f32<<<dim3(2048), 256, 0, stream>>>((float*)d_out, mb, out_size);
        return;
    }

    // ws layout (bytes). diag never aliased.
    char* ws = (char*)d_ws;
    u32*   diag  = (u32*)  (ws + 0);            // 256 B
    u16*   fc1T  = (u16*)  (ws + 256);
    u16*   fc2T  = (u16*)  (ws + 8388864);
    u16*   woT   = (u16*)  (ws + 16777472);
    u16*   wqT   = (u16*)  (ws + 18874624);
    u16*   wkT   = (u16*)  (ws + 20971776);     // contiguous after wqT
    u16*   wvT   = (u16*)  (ws + 23068928);     // contiguous after wkT
    u16*   q_    = (u16*)  (ws + 25166080);
    u16*   k_    = (u16*)  (ws + 41943296);
    u16*   vT_   = (u16*)  (ws + 58720512);
    u16*   qr_   = (u16*)  (ws + 75497728);     // 8650752
    u16*   o_    = (u16*)  (ws + 84148480);     // ..100925696
    u16*   band_ = (u16*)  (ws + 100925696);    // 8388608 -> 109314304
    float* lohi_ = (float*)(ws + 109314304);    // 1048576 -> 110362880
    u64*   mb_   = (u64*)  (ws + 110362880);    // 1048576 -> 111411456
    u16*   xbf_  = (u16*)  (ws + 84148480);     // alias o_ (dead until attn writes it)
    u16*   ao_   = (u16*)  (ws + 58720512);     // alias vT_  [dead after attn]
    u16*   x1_   = (u16*)  (ws + 16777472);     // alias woT..q head [dead then]
    u16*   ff1   = (u16*)  (ws + 33554688);     // alias q tail,k,vT,qr,o [dead]
    u16*   ao2   = (u16*)  (ws + 100663552);    // alias band/lohi/mb [dead after fin]

    init_diag<<<dim3(1), 64, 0, stream>>>((const u16*)x, diag);
    prep_kernel<<<dim3(24576), 256, 0, stream>>>(
        x, xbf_, mask, mb_,
        wq, wk, wv, wo, wqT, wkT, wvT, woT,
        fc1w, fc1T, fc2w, fc2T, diag);

    // fused QKV: B = [wqT|wkT|wvT] (contiguous, 3072x1024); q pre-scaled 0.125
    gemm_qkv<<<dim3(64, 24), 256, 0, stream>>>((const u16*)xbf_, wqT,
                                               bq, bk, bv, q_, k_, vT_, diag);

    qr_mfma<<<dim3(512), 256, 0, stream>>>(q_, rel_k, qr_, diag);
    attn_kernel<<<dim3(512), 256, 0, stream>>>(q_, k_, vT_, qr_, mb_, band_, lohi_, o_, diag);
    fin_mfma<<<dim3(512), 256, 0, stream>>>(band_, lohi_, rel_v, o_, diag);

    gemm_bt<3><<<dim3(64, 8), 256, 0, stream>>>(o_, woT, bo, ao_, 8192, 1024, 1024, 1.0f, diag);
    ln_kernel<<<dim3(8192), 256, 0, stream>>>(x, 1, ao_, ln1g, ln1b, x1_, 0, diag);
    gemm_bt<4><<<dim3(64, 32), 256, 0, stream>>>(x1_, fc1T, fc1b, ff1, 8192, 4096, 1024, 1.0f, diag);
    gemm_bt<3><<<dim3(64, 8), 256, 0, stream>>>(ff1, fc2T, fc2b, ao2, 8192, 1024, 4096, 1.0f, diag);
    ln_kernel<<<dim3(8192), 256, 0, stream>>>(x1_, 0, ao2, ln2g, ln2b, d_out, 1, diag);
}